// Round 22
// baseline (469.837 us; speedup 1.0000x reference)
//
#include <hip/hip_runtime.h>

#define DV   512
#define SV   1024
#define BV   2
#define VV   32000
#define HV   8
#define DFFV 2048
#define NLV  2
#define KCX  25   // exw split-K chunks (klen=1280, %32==0 for 256^2 BK32 kernel)

typedef __bf16 bf16;
typedef __bf16 bf16x4 __attribute__((ext_vector_type(4)));
typedef __bf16 bf16x8 __attribute__((ext_vector_type(8)));
typedef float  f32x4  __attribute__((ext_vector_type(4)));

// async global->LDS DMA, 16 B per lane; LDS dest = wave-uniform base + lane*16
__device__ __forceinline__ void lds_dma16(const void* g, void* l) {
  __builtin_amdgcn_global_load_lds(
      (const __attribute__((address_space(1))) unsigned int*)g,
      (__attribute__((address_space(3))) unsigned int*)l,
      16, 0, 0);
}

// ---------------- wave-per-row LayerNorm, D=512 ----------------
template<typename OUT>
__device__ __forceinline__ void row_ln_512(const float* __restrict__ src,
                                           const float* __restrict__ w,
                                           OUT* __restrict__ dst, int lane) {
  const float4 a = *(const float4*)(src + lane*8);
  const float4 b = *(const float4*)(src + lane*8 + 4);
  float s = a.x+a.y+a.z+a.w + b.x+b.y+b.z+b.w;
  float q = a.x*a.x+a.y*a.y+a.z*a.z+a.w*a.w + b.x*b.x+b.y*b.y+b.z*b.z+b.w*b.w;
#pragma unroll
  for (int off = 32; off > 0; off >>= 1) {
    s += __shfl_down(s, off, 64);
    q += __shfl_down(q, off, 64);
  }
  s = __shfl(s, 0, 64); q = __shfl(q, 0, 64);
  const float mu   = s * (1.0f/512.0f);
  const float rstd = rsqrtf(q * (1.0f/512.0f) - mu*mu + 1e-5f);
  const float4 wa = *(const float4*)(w + lane*8);
  const float4 wb = *(const float4*)(w + lane*8 + 4);
  OUT* d = dst + lane*8;
  d[0] = (OUT)((a.x-mu)*rstd*wa.x);
  d[1] = (OUT)((a.y-mu)*rstd*wa.y);
  d[2] = (OUT)((a.z-mu)*rstd*wa.z);
  d[3] = (OUT)((a.w-mu)*rstd*wa.w);
  d[4] = (OUT)((b.x-mu)*rstd*wb.x);
  d[5] = (OUT)((b.y-mu)*rstd*wb.y);
  d[6] = (OUT)((b.z-mu)*rstd*wb.z);
  d[7] = (OUT)((b.w-mu)*rstd*wb.w);
}

// merged: rows 0..BV*SV-1 = embedding LN (token lookup); rows BV*SV.. = wpe LN -> pn
__global__ void embed_wpe_ln_k(const int* __restrict__ x, const float* __restrict__ wte,
                               const float* __restrict__ wpe, const float* __restrict__ we,
                               const float* __restrict__ wp, float* __restrict__ e,
                               float* __restrict__ pn) {
  const int row = blockIdx.x * 4 + (threadIdx.x >> 6);
  const int lane = threadIdx.x & 63;
  if (row < BV*SV) {
    row_ln_512<float>(wte + (long)x[row] * DV, we, e + (long)row * DV, lane);
  } else {
    const int r = row - BV*SV;
    if (r >= SV + 1) return;
    row_ln_512<float>(wpe + (long)r * DV, wp, pn + (long)r * DV, lane);
  }
}

// ---------------- small prep kernels ----------------
// merged weight casts: Wo (n0), w1 (n1), w2 (n2); all sizes %4 == 0
__global__ void cast3_f2b_k(const float* __restrict__ Wo, const float* __restrict__ w1,
                            const float* __restrict__ w2, bf16* __restrict__ Wob,
                            bf16* __restrict__ w1b, bf16* __restrict__ w2b) {
  const long n0 = (long)NLV*DV*HV*DV, n1 = (long)DFFV*DV, n2 = (long)DV*DFFV;
  long i = ((long)blockIdx.x * 256 + threadIdx.x) * 4;
  const float* in; bf16* o; long r;
  if (i < n0)            { in = Wo; o = Wob; r = i; }
  else if (i < n0 + n1)  { in = w1; o = w1b; r = i - n0; }
  else if (i < n0+n1+n2) { in = w2; o = w2b; r = i - n0 - n1; }
  else return;
  const float4 v = *(const float4*)(in + r);
  bf16x4 ob; ob[0]=(bf16)v.x; ob[1]=(bf16)v.y; ob[2]=(bf16)v.z; ob[3]=(bf16)v.w;
  *(bf16x4*)(&o[r]) = ob;
}

// single-pass wte prep: read fp32 wte once, emit wte_b (cast), wteT_b (transpose-cast),
// and column-sum partials into wmean (caller pre-zeros; divide by V at use)
__global__ void wte_prep_k(const float* __restrict__ wte, bf16* __restrict__ wb,
                           bf16* __restrict__ wbT, float* __restrict__ wm) {
  __shared__ float t[32][33];
  __shared__ float cpart[8][32];
  const int d0 = blockIdx.x * 32, v0 = blockIdx.y * 32;
  const int tx = threadIdx.x, ty = threadIdx.y;
  float csum = 0.f;
#pragma unroll
  for (int k = 0; k < 4; k++) {
    const int vl = ty*4 + k;
    const float val = wte[(long)(v0+vl)*DV + d0+tx];
    t[vl][tx] = val;
    csum += val;
  }
  cpart[ty][tx] = csum;
  __syncthreads();
  const int tid = ty*32 + tx;
  const int r = tid >> 3, c = (tid & 7) * 4;
  { // vectorized cast store, same layout
    bf16x4 o;
    o[0] = (bf16)t[r][c];   o[1] = (bf16)t[r][c+1];
    o[2] = (bf16)t[r][c+2]; o[3] = (bf16)t[r][c+3];
    *(bf16x4*)(&wb[(long)(v0+r)*DV + d0+c]) = o;
  }
  { // vectorized transposed store
    bf16x4 o;
    o[0] = (bf16)t[c][r];   o[1] = (bf16)t[c+1][r];
    o[2] = (bf16)t[c+2][r]; o[3] = (bf16)t[c+3][r];
    *(bf16x4*)(&wbT[(long)(d0+r)*VV + v0+c]) = o;
  }
  if (ty == 0) {
    float s = 0.f;
#pragma unroll
    for (int k = 0; k < 8; k++) s += cpart[k][tx];
    atomicAdd(&wm[d0+tx], s);
  }
}

__global__ void qk_prep_k(const float* __restrict__ pn, const float* __restrict__ Wq,
                          const float* __restrict__ Wk, bf16* __restrict__ Qh,
                          bf16* __restrict__ Kh) {
  const int s = blockIdx.x, hh = blockIdx.y;
  const int d = threadIdx.x * 4;
  const float4 q  = *(const float4*)(pn + (long)(s+1)*DV + d);
  const float4 kk = *(const float4*)(pn + (long)s*DV + d);
  const float4 aq = *(const float4*)(Wq + (long)hh*DV + d);
  const float4 ak = *(const float4*)(Wk + (long)hh*DV + d);
  const long o = ((long)hh*SV + s)*DV + d;
  Qh[o+0]=(bf16)(q.x*aq.x);  Qh[o+1]=(bf16)(q.y*aq.y);
  Qh[o+2]=(bf16)(q.z*aq.z);  Qh[o+3]=(bf16)(q.w*aq.w);
  Kh[o+0]=(bf16)(kk.x*ak.x); Kh[o+1]=(bf16)(kk.y*ak.y);
  Kh[o+2]=(bf16)(kk.z*ak.z); Kh[o+3]=(bf16)(kk.w*ak.w);
}

// fused: f_k (+)= sum of KC slices (init=1: overwrite, skip f_k read);
// hbuf = LN(f_k) * w   (one wave per row)
__global__ void freduce_ln_k(const float* __restrict__ part, float* __restrict__ f_k,
                             const float* __restrict__ w, bf16* __restrict__ hbuf,
                             int KC, int init) {
  const int row = blockIdx.x * 4 + (threadIdx.x >> 6);
  const int lane = threadIdx.x & 63;
  const int b = row >> 10;                     // SV = 1024
  const long ro = (long)row * DV + lane*8;
  const long po = (long)(row & (SV-1)) * DV + lane*8;
  float v[8];
  if (init) {
#pragma unroll
    for (int k = 0; k < 8; k++) v[k] = 0.f;
  } else {
    const float4 a = *(const float4*)(f_k + ro);
    const float4 c = *(const float4*)(f_k + ro + 4);
    v[0]=a.x;v[1]=a.y;v[2]=a.z;v[3]=a.w;v[4]=c.x;v[5]=c.y;v[6]=c.z;v[7]=c.w;
  }
  for (int c = 0; c < KC; c++) {
    const float* pp = part + ((long)(b*KC + c))*SV*DV + po;
    const float4 a = *(const float4*)pp;
    const float4 d = *(const float4*)(pp + 4);
    v[0]+=a.x;v[1]+=a.y;v[2]+=a.z;v[3]+=a.w;v[4]+=d.x;v[5]+=d.y;v[6]+=d.z;v[7]+=d.w;
  }
  { float4 o1={v[0],v[1],v[2],v[3]}, o2={v[4],v[5],v[6],v[7]};
    *(float4*)(f_k + ro) = o1; *(float4*)(f_k + ro + 4) = o2; }
  float s = 0.f, q = 0.f;
#pragma unroll
  for (int k = 0; k < 8; k++) { s += v[k]; q += v[k]*v[k]; }
#pragma unroll
  for (int off = 32; off > 0; off >>= 1) {
    s += __shfl_down(s, off, 64);
    q += __shfl_down(q, off, 64);
  }
  s = __shfl(s, 0, 64); q = __shfl(q, 0, 64);
  const float mu   = s * (1.0f/512.0f);
  const float rstd = rsqrtf(q * (1.0f/512.0f) - mu*mu + 1e-5f);
  const float4 wa = *(const float4*)(w + lane*8);
  const float4 wb = *(const float4*)(w + lane*8 + 4);
  bf16* d = hbuf + (long)row * DV + lane*8;
  d[0] = (bf16)((v[0]-mu)*rstd*wa.x);
  d[1] = (bf16)((v[1]-mu)*rstd*wa.y);
  d[2] = (bf16)((v[2]-mu)*rstd*wa.z);
  d[3] = (bf16)((v[3]-mu)*rstd*wa.w);
  d[4] = (bf16)((v[4]-mu)*rstd*wb.x);
  d[5] = (bf16)((v[5]-mu)*rstd*wb.y);
  d[6] = (bf16)((v[6]-mu)*rstd*wb.z);
  d[7] = (bf16)((v[7]-mu)*rstd*wb.w);
}

// fused: f_k += sum of KC slices; bf16 mirror write
__global__ void freduce_cast_k(const float* __restrict__ part, float* __restrict__ f_k,
                               bf16* __restrict__ fb, int KC) {
  const long i = ((long)blockIdx.x * 256 + threadIdx.x) * 4;
  const int  b = (int)(i / ((long)SV*DV));
  const long r = i % ((long)SV*DV);
  float4 acc = *(const float4*)(f_k + i);
  for (int c = 0; c < KC; c++) {
    const float4 v = *(const float4*)(part + ((long)(b*KC + c))*SV*DV + r);
    acc.x += v.x; acc.y += v.y; acc.z += v.z; acc.w += v.w;
  }
  *(float4*)(f_k + i) = acc;
  bf16x4 o; o[0]=(bf16)acc.x; o[1]=(bf16)acc.y; o[2]=(bf16)acc.z; o[3]=(bf16)acc.w;
  *(bf16x4*)(&fb[i]) = o;
}

// Vt = e - (sum of KCX bf16 exw partial slices)/colsum, transposed (D,S) bf16 out.
// colsum computed inline from the 250 v-block partials (part is L2-resident, 1 MB).
__global__ void vt_part_k(const float* __restrict__ e, const bf16* __restrict__ pb,
                          const float* __restrict__ part, bf16* __restrict__ VtT) {
  __shared__ float t[32][33];
  __shared__ float cpart[8][32];
  __shared__ float csum[32];
  const int d0 = blockIdx.x * 32, s0 = blockIdx.y * 32;
  const int tx = threadIdx.x, ty = threadIdx.y;
  { // cooperative colsum for s0..s0+31
    float cs = 0.f;
    for (int v = ty; v < VV/128; v += 8) cs += part[(long)v * SV + s0 + tx];
    cpart[ty][tx] = cs;
  }
  __syncthreads();
  if (ty == 0) {
    float s = 0.f;
#pragma unroll
    for (int k = 0; k < 8; k++) s += cpart[k][tx];
    csum[tx] = s;
  }
  __syncthreads();
#pragma unroll
  for (int k = 0; k < 4; k++) {
    const int sl = ty + k*8;
    const long off = (long)(s0+sl)*DV + d0+tx;
    float acc = 0.f;
    for (int c = 0; c < KCX; c++) acc += (float)pb[(long)c*SV*DV + off];
    t[sl][tx] = e[off] - acc / csum[sl];
  }
  __syncthreads();
#pragma unroll
  for (int k = 0; k < 4; k++) {
    const int dl = ty + k*8;
    VtT[(long)(d0+dl)*SV + s0+tx] = (bf16)t[tx][dl];
  }
}

// layer-0 variant: ex_wte is the wte column-mean (uniform softmax), exact algebra
// (z = batch)
__global__ void vt0_transpose_k(const float* __restrict__ e, const float* __restrict__ wm,
                                bf16* __restrict__ VtT) {
  __shared__ float t[32][33];
  const int d0 = blockIdx.x * 32, s0 = blockIdx.y * 32, b = blockIdx.z;
  const int tx = threadIdx.x, ty = threadIdx.y;
  const float* eb = e + (long)b*SV*DV;
  bf16* vb = VtT + (long)b*DV*SV;
  const float mval = wm[d0 + tx] * (1.0f / (float)VV);
#pragma unroll
  for (int k = 0; k < 4; k++) {
    const int sl = ty + k*8;
    t[sl][tx] = eb[(long)(s0+sl)*DV + d0+tx] - mval;
  }
  __syncthreads();
#pragma unroll
  for (int k = 0; k < 4; k++) {
    const int dl = ty + k*8;
    vb[(long)(d0+dl)*SV + s0+tx] = (bf16)t[tx][dl];
  }
}

// ---------------- layer-1 last-row-only tail (everything after the Wo add is
// row-wise, and only row SV-1 feeds the output logits) ----------------

// U[b][h*DV+d] = dot(krn[h][SV-1][:], VtT[b][d][:])   (wave per output)
__global__ void u_last_k(const bf16* __restrict__ krn, const bf16* __restrict__ VtT,
                         bf16* __restrict__ u) {
  const int wv = threadIdx.x >> 6, lane = threadIdx.x & 63;
  const int d = blockIdx.x * 4 + wv;
  const int h = blockIdx.y, b = blockIdx.z;
  const bf16* kr = krn + (long)h*SV*SV + (long)(SV-1)*SV;
  const bf16* vr = VtT + (long)b*DV*SV + (long)d*SV;
  float acc = 0.f;
#pragma unroll
  for (int it = 0; it < 2; it++) {
    const int k = lane*8 + it*512;
    const bf16x8 a = *(const bf16x8*)(kr + k);
    const bf16x8 v = *(const bf16x8*)(vr + k);
#pragma unroll
    for (int i = 0; i < 8; i++) acc += (float)a[i] * (float)v[i];
  }
#pragma unroll
  for (int off = 32; off > 0; off >>= 1) acc += __shfl_down(acc, off, 64);
  if (lane == 0) u[((long)b*HV + h)*DV + d] = (bf16)acc;
}

// out[b][m] = act(dot(vec[b], W[m,:]))  (wave per output; W (M,K) bf16 row-major)
// ACT: 0 = none -> f32 out, 1 = gelu -> bf16 out
template<int ACT>
__global__ void gemv_k(const bf16* __restrict__ W, const bf16* __restrict__ vec,
                       float* __restrict__ outf, bf16* __restrict__ outb,
                       int M, int K, long sVb) {
  const int wv = threadIdx.x >> 6, lane = threadIdx.x & 63;
  const int m = blockIdx.x * 4 + wv;
  const int b = blockIdx.y;
  if (m >= M) return;
  const bf16* wr = W + (long)m * K;
  const bf16* vb = vec + (long)b * sVb;
  float acc = 0.f;
  for (int k = lane*8; k < K; k += 512) {
    const bf16x8 a = *(const bf16x8*)(wr + k);
    const bf16x8 v = *(const bf16x8*)(vb + k);
#pragma unroll
    for (int i = 0; i < 8; i++) acc += (float)a[i] * (float)v[i];
  }
#pragma unroll
  for (int off = 32; off > 0; off >>= 1) acc += __shfl_down(acc, off, 64);
  if (lane == 0) {
    if (ACT == 0) outf[(long)b * M + m] = acc;
    else {
      const float ge = 0.5f * acc * (1.0f + erff(acc * 0.70710678118f));
      outb[(long)b * M + m] = (bf16)ge;
    }
  }
}

// f_last = f_k[b][SV-1] + delta; h = LN(f_last) * w   (one wave per batch)
__global__ void mid_ln_k(const float* __restrict__ f_k, const float* __restrict__ delta,
                         const float* __restrict__ w, float* __restrict__ f_last,
                         bf16* __restrict__ h) {
  const int b = threadIdx.x >> 6;
  if (b >= BV) return;
  const int lane = threadIdx.x & 63;
  const long ro = ((long)b * SV + (SV - 1)) * DV + lane*8;
  const float* dp = delta + (long)b * DV + lane*8;
  float v[8];
  { const float4 a = *(const float4*)(f_k + ro);
    const float4 c = *(const float4*)(f_k + ro + 4);
    const float4 da = *(const float4*)dp;
    const float4 db = *(const float4*)(dp + 4);
    v[0]=a.x+da.x; v[1]=a.y+da.y; v[2]=a.z+da.z; v[3]=a.w+da.w;
    v[4]=c.x+db.x; v[5]=c.y+db.y; v[6]=c.z+db.z; v[7]=c.w+db.w; }
  { float* fl = f_last + (long)b*DV + lane*8;
    float4 o1={v[0],v[1],v[2],v[3]}, o2v={v[4],v[5],v[6],v[7]};
    *(float4*)fl = o1; *(float4*)(fl+4) = o2v; }
  float s = 0.f, q = 0.f;
#pragma unroll
  for (int k = 0; k < 8; k++) { s += v[k]; q += v[k]*v[k]; }
#pragma unroll
  for (int off = 32; off > 0; off >>= 1) {
    s += __shfl_down(s, off, 64);
    q += __shfl_down(q, off, 64);
  }
  s = __shfl(s, 0, 64); q = __shfl(q, 0, 64);
  const float mu   = s * (1.0f/512.0f);
  const float rstd = rsqrtf(q * (1.0f/512.0f) - mu*mu + 1e-5f);
  const float4 wa = *(const float4*)(w + lane*8);
  const float4 wb = *(const float4*)(w + lane*8 + 4);
  bf16* d = h + (long)b * DV + lane*8;
  d[0] = (bf16)((v[0]-mu)*rstd*wa.x);
  d[1] = (bf16)((v[1]-mu)*rstd*wa.y);
  d[2] = (bf16)((v[2]-mu)*rstd*wa.z);
  d[3] = (bf16)((v[3]-mu)*rstd*wa.w);
  d[4] = (bf16)((v[4]-mu)*rstd*wb.x);
  d[5] = (bf16)((v[5]-mu)*rstd*wb.y);
  d[6] = (bf16)((v[6]-mu)*rstd*wb.z);
  d[7] = (bf16)((v[7]-mu)*rstd*wb.w);
}

// obuf[b] = LN(f_last[b] + o2[b]) * w   (one wave per batch)
__global__ void final2_k(const float* __restrict__ f_last, const float* __restrict__ o2,
                         const float* __restrict__ w, float* __restrict__ obuf) {
  const int b = threadIdx.x >> 6;
  if (b >= BV) return;
  const int lane = threadIdx.x & 63;
  const float* fl = f_last + (long)b * DV + lane*8;
  const float* op = o2 + (long)b * DV + lane*8;
  float v[8];
  { const float4 a = *(const float4*)fl;
    const float4 c = *(const float4*)(fl + 4);
    const float4 da = *(const float4*)op;
    const float4 db = *(const float4*)(op + 4);
    v[0]=a.x+da.x; v[1]=a.y+da.y; v[2]=a.z+da.z; v[3]=a.w+da.w;
    v[4]=c.x+db.x; v[5]=c.y+db.y; v[6]=c.z+db.z; v[7]=c.w+db.w; }
  float s = 0.f, q = 0.f;
#pragma unroll
  for (int k = 0; k < 8; k++) { s += v[k]; q += v[k]*v[k]; }
#pragma unroll
  for (int off = 32; off > 0; off >>= 1) {
    s += __shfl_down(s, off, 64);
    q += __shfl_down(q, off, 64);
  }
  s = __shfl(s, 0, 64); q = __shfl(q, 0, 64);
  const float mu   = s * (1.0f/512.0f);
  const float rstd = rsqrtf(q * (1.0f/512.0f) - mu*mu + 1e-5f);
  const float4 wa = *(const float4*)(w + lane*8);
  const float4 wb = *(const float4*)(w + lane*8 + 4);
  float* d = obuf + (long)b * DV + lane*8;
  d[0] = (v[0]-mu)*rstd*wa.x;
  d[1] = (v[1]-mu)*rstd*wa.y;
  d[2] = (v[2]-mu)*rstd*wa.z;
  d[3] = (v[3]-mu)*rstd*wa.w;
  d[4] = (v[4]-mu)*rstd*wb.x;
  d[5] = (v[5]-mu)*rstd*wb.y;
  d[6] = (v[6]-mu)*rstd*wb.z;
  d[7] = (v[7]-mu)*rstd*wb.w;
}

// both batches in one pass over wte (fp32 kept for accuracy)
__global__ void logits_k(const float* __restrict__ obuf, const float* __restrict__ wte,
                         float* __restrict__ out, int V) {
  const int wv = threadIdx.x >> 6, lane = threadIdx.x & 63;
  const int v = blockIdx.x * 4 + wv;
  const float* wr = wte + (long)v * DV;
  const float4 a  = *(const float4*)(wr + lane*8);
  const float4 c  = *(const float4*)(wr + lane*8 + 4);
  const float4 oa0 = *(const float4*)(obuf + lane*8);
  const float4 ob0 = *(const float4*)(obuf + lane*8 + 4);
  const float4 oa1 = *(const float4*)(obuf + DV + lane*8);
  const float4 ob1 = *(const float4*)(obuf + DV + lane*8 + 4);
  float d0 = a.x*oa0.x + a.y*oa0.y + a.z*oa0.z + a.w*oa0.w
           + c.x*ob0.x + c.y*ob0.y + c.z*ob0.z + c.w*ob0.w;
  float d1 = a.x*oa1.x + a.y*oa1.y + a.z*oa1.z + a.w*oa1.w
           + c.x*ob1.x + c.y*ob1.y + c.z*ob1.z + c.w*ob1.w;
#pragma unroll
  for (int off = 32; off > 0; off >>= 1) {
    d0 += __shfl_down(d0, off, 64);
    d1 += __shfl_down(d1, off, 64);
  }
  if (lane == 0) { out[v] = d0; out[(long)V + v] = d1; }
}

// bijective XCD swizzle (m204): hw linear id -> work id, contiguous chunk per XCD
__device__ __forceinline__ long xcd_swz(long lin, long nwg) {
  const long qq = nwg >> 3, rr = nwg & 7;
  const long xcd = lin & 7, idx = lin >> 3;
  return (xcd < rr ? xcd * (qq + 1) : rr * (qq + 1) + (xcd - rr) * qq) + idx;
}

// ---------------- NT MFMA GEMM: C[m,n] = sum_k A[m,k]*B[n,k] ----------------
// 128x128x32 tile, double-buffered LDS (32 KiB total -> 4-5 blocks/CU),
// counted-vmcnt 2-phase pipeline, bijective XCD swizzle, both-sides XOR bank
// swizzle for 64 B rows: LDS[r][s] holds global slot s^((r>>1)&3).
// EPI: 2=store bf16,
//      3=causal mask * wn[m]*scale -> bf16 (krn build; fully-masked tiles skipped),
//      4=gelu -> bf16,
//      6=f32 partial-slice store (split-K, slice = b*KC+chunk, stride sCh)
struct GemmArgs {
  const bf16* A; const bf16* B;
  float* Cf; bf16* Cb;
  int K, lda, ldb, ldc;
  long sAh, sAb, sBh, sBb, sCh, sCb;
  int Hmod, KC, causal, swap;
  float scale;
};

template<int EPI>
__global__ __launch_bounds__(256)
void gemm_nt(GemmArgs g) {
  __shared__ bf16 As[2][128*32];
  __shared__ bf16 Bs[2][128*32];
  const int tid = threadIdx.x;
  int bx = blockIdx.x, by = blockIdx.y, z = blockIdx.z;
  {
    const int nbx = gridDim.x, nby = gridDim.y;
    const long nwg = (long)nbx * nby * gridDim.z;
    long lin = xcd_swz(bx + (long)nbx * (by + (long)nby * z), nwg);
    bx = (int)(lin % nbx);
    const long t2 = lin / nbx;
    by = (int)(t2 % nby);
    z  = (int)(t2 / nby);
  }
  const int chunk = z % g.KC;
  const int zo = z / g.KC;
  const int h = zo % g.Hmod;
  const int b = zo / g.Hmod;
  if (g.swap) { int t = bx; bx = by; by = t; }
  const int m0 = by * 128;
  const int n0 = bx * 128;
  const long coff = (long)h * g.sCh + (long)b * g.sCb;

  if (EPI == 3 && n0 > m0 + 127) return;  // fully-masked krn tile: never read downstream

  const bf16* A = g.A + (long)h * g.sAh + (long)b * g.sAb;
  const bf16* B = g.B + (long)h * g.sBh + (long)b * g.sBb;
  const int lane = tid & 63;
  const int wv = tid >> 6;
  const int wm = (wv >> 1) * 64;
  const int wn = (wv & 1) * 64;
  const int frow = lane & 15;
  const int quad = lane >> 4;
  const int sg8  = ((lane & 3) ^ ((lane >> 3) & 3)) * 8;
  const int drow = lane >> 2;

  const f32x4 fzero = {0.f, 0.f, 0.f, 0.f};
  f32x4 acc[4][4];
#pragma unroll
  for (int i = 0; i < 4; i++)
#pragma unroll
    for (int j = 0; j < 4; j++) acc[i][j] = fzero;

  int k0, klen;
  if (g.causal) { k0 = 0; klen = min(g.K, m0 + 128); }
  else          { klen = g.K / g.KC; k0 = chunk * klen; }

  auto stage = [&](int buf, int kk) {
#pragma unroll
    for (int c = 0; c < 2; c++) {
      const int rb = c*64 + wv*16;
      lds_dma16(A + (long)(m0 + rb + drow) * g.lda + kk + sg8, &As[buf][rb*32]);
      lds_dma16(B + (long)(n0 + rb + drow) * g.ldb + kk + sg8, &Bs[buf][rb*32]);
    }
  };

  const int nsteps = klen >> 5;  // all callers: klen % 32 == 0
  int cur = 0;
  stage(0, k0);
  for (int it = 0; it < nsteps; ++it) {
    if (it + 1 < nsteps) {
      stage(cur ^ 1, k0 + (it + 1) * 32);
      asm volatile("s_waitcnt vmcnt(4)" ::: "memory");  // cur's 4 landed, next's 4 fly
    } else {
      asm volatile("s_waitcnt vmcnt(0)" ::: "memory");
    }
    __builtin_amdgcn_s_barrier();
    bf16x8 af[4], bfr[4];
    const int sw = (frow >> 1) & 3;
#pragma unroll
    for (int i = 0; i < 4; i++)
      af[i] = *(const bf16x8*)(&As[cur][(wm + i*16 + frow)*32 + ((quad ^ sw))*8]);
#pragma unroll
    for (int j = 0; j < 4; j++)
      bfr[j] = *(const bf16x8*)(&Bs[cur][(wn + j*16 + frow)*32 + ((quad ^ sw))*8]);
#pragma unroll
    for (int i = 0; i < 4; i++)
#pragma unroll
      for (int j = 0; j < 4; j++)
        acc[i][j] = __builtin_amdgcn_mfma_f32_16x16x32_bf16(af[i], bfr[j], acc[i][j], 0, 0, 0);
    __builtin_amdgcn_s_barrier();
    cur ^= 1;
  }

  const int rb = quad * 4;
#pragma unroll
  for (int i = 0; i < 4; i++) {
#pragma unroll
    for (int j = 0; j < 4; j++) {
#pragma unroll
      for (int r = 0; r < 4; r++) {
        const int gm = m0 + wm + i*16 + rb + r;
        const int gn = n0 + wn + j*16 + frow;
        const float v = acc[i][j][r];
        if (EPI == 2) {
          g.Cb[coff + (long)gm * g.ldc + gn] = (bf16)v;
        } else if (EPI == 3) {
          const float val = (gn <= gm) ? v * g.scale / (float)(gm + 1) : 0.0f;
          g.Cb[coff + (long)gm * g.ldc + gn] = (bf16)val;
        } else if (EPI == 4) {
          const float ge = 0.5f * v * (1.0f + erff(v * 0.70710678118f));
          g.Cb[coff + (long)gm * g.ldc + gn] = (bf16)ge;
        } else if (EPI == 6) {
          g.Cf[(long)(b*g.KC + chunk) * g.sCh + (long)gm * g.ldc + gn] = v;
        }
      }
    }
  }
}

// ---------------- 256x256x32 8-wave NT GEMM ------------
// BK=32 (was 64): LDS 64 KiB -> 2 blocks/CU. Counters (r21) showed the BK=64
// version stall-bound at 1 block/CU: MfmaUtil 21%, HBM 21%, Occ 17% -- with a
// co-resident block the vmcnt+barrier stall overlaps with the other block's
// compute (same mechanism as gemm_nt at 4-5 blocks/CU; cf. m132).
// Rows are 64 B = 4 x 16B slots, both-sides XOR swizzle slot^((row>>1)&3)
// (gemm_nt's proven 64-B-row pattern). Counted-vmcnt 2-phase pipeline,
// m-tiles on grid x (fastest) -> B-panel sharers contiguous -> one XCD L2.
// EPI: 5 = exp -> bf16 C + per-128-col-block partial row-sums into Cf[vblk*SV+m]
//      7 = bf16 partial-slice store (split-K, slice = z, stride sCh)
template<int EPI>
__global__ __launch_bounds__(512)
void gemm256(GemmArgs g) {
  __shared__ bf16 As[2][256*32];
  __shared__ bf16 Bs[2][256*32];
  const int tid = threadIdx.x;
  int bm = blockIdx.x, bn = blockIdx.y, z = blockIdx.z;   // m fastest
  {
    const int nbx = gridDim.x, nby = gridDim.y;
    const long nwg = (long)nbx * nby * gridDim.z;
    long lin = xcd_swz(bm + (long)nbx * (bn + (long)nby * z), nwg);
    bm = (int)(lin % nbx);
    const long t2 = lin / nbx;
    bn = (int)(t2 % nby);
    z  = (int)(t2 / nby);
  }
  const int m0 = bm * 256, n0 = bn * 256;
  const int lane = tid & 63, wv = tid >> 6;
  const int wm = (wv >> 2) * 128, wn = (wv & 3) * 64;
  const int frow = lane & 15, quad = lane >> 4;
  // staging: per instr 16 rows of 64 B; lane -> (row=lane>>2, slot lane&3)
  const int sg8  = ((lane & 3) ^ ((lane >> 3) & 3)) * 8;
  const int drow = lane >> 2;

  const f32x4 fzero = {0.f, 0.f, 0.f, 0.f};
  f32x4 acc[8][4];
#pragma unroll
  for (int i = 0; i < 8; i++)
#pragma unroll
    for (int j = 0; j < 4; j++) acc[i][j] = fzero;

  const int klen = g.K / g.KC;
  const int k0 = z * klen;

  auto stage = [&](int buf, int kk) {
#pragma unroll
    for (int c = 0; c < 2; c++) {
      const int rb = c*128 + wv*16;
      lds_dma16(g.A + (long)(m0 + rb + drow) * g.lda + kk + sg8, &As[buf][rb*32]);
      lds_dma16(g.B + (long)(n0 + rb + drow) * g.ldb + kk + sg8, &Bs[buf][rb*32]);
    }
  };

  const int nsteps = klen >> 5;  // callers: klen % 32 == 0 (512, 1280)
  int cur = 0;
  stage(0, k0);
  for (int it = 0; it < nsteps; ++it) {
    if (it + 1 < nsteps) {
      stage(cur ^ 1, k0 + (it + 1) * 32);
      asm volatile("s_waitcnt vmcnt(4)" ::: "memory");  // cur's 4 landed, next's 4 fly
    } else {
      asm volatile("s_waitcnt vmcnt(0)" ::: "memory");
    }
    __builtin_amdgcn_s_barrier();
    const int sw = (frow >> 1) & 3;
    bf16x8 af[8], bfr[4];
#pragma unroll
    for (int j = 0; j < 4; j++)
      bfr[j] = *(const bf16x8*)(&Bs[cur][(wn + j*16 + frow)*32 + ((quad ^ sw))*8]);
#pragma unroll
    for (int i = 0; i < 8; i++)
      af[i] = *(const bf16x8*)(&As[cur][(wm + i*16 + frow)*32 + ((quad ^ sw))*8]);
#pragma unroll
    for (int i = 0; i < 8; i++)
#pragma unroll
      for (int j = 0; j < 4; j++)
        acc[i][j] = __builtin_amdgcn_mfma_f32_16x16x32_bf16(af[i], bfr[j], acc[i][j], 0, 0, 0);
    __builtin_amdgcn_s_barrier();
    cur ^= 1;
  }

  const int rb4 = quad * 4;
  if (EPI == 5) {
    const int vblk = (n0 + wn) >> 7;   // wave's 64-col slice lies in one 128-v block
#pragma unroll
    for (int i = 0; i < 8; i++) {
#pragma unroll
      for (int r = 0; r < 4; r++) {
        const int gm = m0 + wm + i*16 + rb4 + r;
        float rs = 0.f;
#pragma unroll
        for (int j = 0; j < 4; j++) {
          const int gn = n0 + wn + j*16 + frow;
          const float ev = __expf(acc[i][j][r]);
          g.Cb[(long)gm * g.ldc + gn] = (bf16)ev;
          rs += ev;
        }
#pragma unroll
        for (int off = 1; off < 16; off <<= 1)
          rs += __shfl_xor(rs, off, 64);
        if (frow == 0) atomicAdd(g.Cf + (long)vblk * SV + gm, rs);
      }
    }
  } else {  // EPI == 7
#pragma unroll
    for (int i = 0; i < 8; i++) {
#pragma unroll
      for (int j = 0; j < 4; j++) {
#pragma unroll
        for (int r = 0; r < 4; r++) {
          const int gm = m0 + wm + i*16 + rb4 + r;
          const int gn = n0 + wn + j*16 + frow;
          g.Cb[(long)z * g.sCh + (long)gm * g.ldc + gn] = (bf16)acc[i][j][r];
        }
      }
    }
  }
}

// layer-0 tail: U_rs -> Wo(partial+fused reduce/LN) -> MLP(partial+fused reduce+cast)
static void layer_tail0(bf16* krn, bf16* VtT, bf16* U_rs, bf16* Wo_b,
                        float* f_k, bf16* f_k_b, bf16* hbuf, bf16* Gbuf, float* fpart,
                        bf16* w1_b, bf16* w2_b, const float* lnmw, hipStream_t stream) {
  { // U_rs[b][s, h*D+d] = sum_t krn[h,s,t] * Vt[b,t,d]  (causal K-truncation)
    GemmArgs g = {};
    g.A = krn; g.B = VtT; g.Cb = U_rs;
    g.K = SV; g.lda = SV; g.ldb = SV; g.ldc = HV*DV;
    g.sAh = (long)SV*SV; g.sBb = (long)DV*SV;
    g.sCh = DV; g.sCb = (long)SV*HV*DV;
    g.Hmod = HV; g.KC = 1; g.causal = 1;
    gemm_nt<2><<<dim3(DV/128, SV/128, BV*HV), 256, 0, stream>>>(g);
  }
  { // fpart[b*8+c] = partial of U_rs @ Wo[0]^T  (split-K=8, plain stores)
    GemmArgs g = {};
    g.A = U_rs; g.B = Wo_b; g.Cf = fpart;
    g.K = HV*DV; g.lda = HV*DV; g.ldb = HV*DV; g.ldc = DV;
    g.sAb = (long)SV*HV*DV; g.sCh = (long)SV*DV;
    g.Hmod = 1; g.KC = 8; g.causal = 0;
    gemm_nt<6><<<dim3(DV/128, SV/128, BV*8), 256, 0, stream>>>(g);
  }
  freduce_ln_k<<<dim3(BV*SV/4), 256, 0, stream>>>(fpart, f_k, lnmw, hbuf, 8, 1);
  { // Gbuf = gelu(h @ w1^T)
    GemmArgs g = {};
    g.A = hbuf; g.B = w1_b; g.Cb = Gbuf;
    g.K = DV; g.lda = DV; g.ldb = DV; g.ldc = DFFV;
    g.sAb = (long)SV*DV; g.sCb = (long)SV*DFFV;
    g.Hmod = 1; g.KC = 1; g.causal = 0;
    gemm_nt<4><<<dim3(DFFV/128, SV/128, BV), 256, 0, stream>>>(g);
  }
  { // fpart[b*8+c] = partial of Gbuf @ w2^T  (split-K=8, plain stores)
    GemmArgs g = {};
    g.A = Gbuf; g.B = w2_b; g.Cf = fpart;
    g.K = DFFV; g.lda = DFFV; g.ldb = DFFV; g.ldc = DV;
    g.sAb = (long)SV*DFFV; g.sCh = (long)SV*DV;
    g.Hmod = 1; g.KC = 8; g.causal = 0;
    gemm_nt<6><<<dim3(DV/128, SV/128, BV*8), 256, 0, stream>>>(g);
  }
  freduce_cast_k<<<dim3(BV*SV*DV/4/256), 256, 0, stream>>>(fpart, f_k, f_k_b, 8);
}

extern "C" void kernel_launch(void* const* d_in, const int* in_sizes, int n_in,
                              void* d_out, int out_size, void* d_ws, size_t ws_size,
                              hipStream_t stream) {
  const int*   x    = (const int*)d_in[0];
  const float* wte  = (const float*)d_in[1];
  const float* wpe  = (const float*)d_in[2];
  const float* lnew = (const float*)d_in[3];
  const float* lnpw = (const float*)d_in[4];
  const float* lnfw = (const float*)d_in[5];
  const float* lnmw = (const float*)d_in[6];
  const float* Wq   = (const float*)d_in[7];
  const float* Wk   = (const float*)d_in[8];
  const float* Wo   = (const float*)d_in[9];
  const float* w1   = (const float*)d_in[10];
  const float* w2   = (const float*)d_in[11];
  float* out = (float*)d_out;
  (void)in_sizes; (void)n_in; (void)out_size; (void)ws_size;

  char* p = (char*)d_ws;
  auto alloc = [&](size_t bytes) -> void* {
    void* r = (void*)p;
    p += (bytes + 255) & ~(size_t)255;
    return r;
  };
  // persistent buffers (~155 MB)
  float* e      = (float*)alloc((size_t)BV*SV*DV*4);
  float* pn     = (float*)alloc((size_t)(SV+1)*DV*4);
  bf16*  wteT_b = (bf16*)alloc((size_t)DV*VV*2);
  bf16*  wte_b  = (bf16*)alloc((size_t)VV*DV*2);
  bf16*  krn    = (bf16*)alloc((size_t)HV*SV*SV*2);
  bf16*  Wo_b   = (bf16*)alloc((size_t)NLV*DV*HV*DV*2);
  bf16*  w1_b   = (bf16*)alloc((size_t)DFFV*DV*2);
  bf16*  w2_b   = (bf16*)alloc((size_t)DV*DFFV*2);
  float* f_k    = (float*)alloc((size_t)BV*SV*DV*4);
  bf16*  f_k_b  = (bf16*)alloc((size_t)BV*SV*DV*2);
  bf16*  expart = (bf16*)alloc((size_t)KCX*SV*DV*2);     // 26 MB exw bf16 partial slices
  bf16*  VtT    = (bf16*)alloc((size_t)BV*DV*SV*2);
  bf16*  hbuf   = (bf16*)alloc((size_t)BV*SV*DV*2);
  float* part   = (float*)alloc((size_t)BV*(VV/128)*SV*4); // 2 MB partial colsums [b][vblk][s]
  float* obuf   = (float*)alloc((size_t)BV*DV*4);
  float* wmean  = (float*)alloc((size_t)DV*4);
  // last-row tail buffers (tiny)
  bf16*  u_last = (bf16*)alloc((size_t)BV*HV*DV*2);
  float* delta  = (float*)alloc((size_t)BV*DV*4);
  float* f_last = (float*)alloc((size_t)BV*DV*4);
  bf16*  h_last = (bf16*)alloc((size_t)BV*DV*2);
  bf16*  g_last = (bf16*)alloc((size_t)BV*DFFV*2);
  float* o2buf  = (float*)alloc((size_t)BV*DV*4);
  // arena (65.5 MB), time-sliced: {Qh,Kh} -> tail{U_rs,Gbuf,fpart} -> PT
  char*  arena  = (char*)alloc((size_t)SV*VV*2);
  bf16*  Qh     = (bf16*)arena;
  bf16*  Kh     = (bf16*)(arena + (size_t)HV*SV*DV*2);
  bf16*  PT     = (bf16*)arena;                            // (S,V) unnormalized probs
  bf16*  U_rs   = (bf16*)arena;                            // [0, 16.8 MB)
  bf16*  Gbuf   = (bf16*)(arena + (size_t)BV*SV*HV*DV*2);  // [16.8, 25.2 MB)
  float* fpart  = (float*)(arena + (size_t)BV*SV*HV*DV*2 + (size_t)BV*SV*DFFV*2); // [25.2, 58.7)

  // ---- prologue ----
  hipMemsetAsync(wmean, 0, (size_t)DV*4, stream);
  hipMemsetAsync(part, 0, (size_t)BV*(VV/128)*SV*4, stream);
  wte_prep_k<<<dim3(DV/32, VV/32), dim3(32,8), 0, stream>>>(wte, wte_b, wteT_b, wmean);
  cast3_f2b_k<<<dim3((NLV*DV*HV*DV + DFFV*DV + DV*DFFV)/4/256), 256, 0, stream>>>(
      Wo, w1, w2, Wo_b, w1_b, w2_b);
  embed_wpe_ln_k<<<dim3((BV*SV + SV+1 + 3)/4), 256, 0, stream>>>(
      x, wte, wpe, lnew, lnpw, e, pn);
  qk_prep_k<<<dim3(SV, HV), 128, 0, stream>>>(pn, Wq, Wk, Qh, Kh);

  { // krn[h,s,t] = mask(t<=s) * (Q.K)/sqrt(D) * wn[s]  -> bf16 (masked tiles skipped)
    GemmArgs g = {};
    g.A = Qh; g.B = Kh; g.Cb = krn;
    g.K = DV; g.lda = DV; g.ldb = DV; g.ldc = SV;
    g.sAh = (long)SV*DV; g.sBh = (long)SV*DV; g.sCh = (long)SV*SV;
    g.Hmod = HV; g.KC = 1; g.causal = 0;
    g.scale = 0.044194173824159216f;  // 1/sqrt(512)
    gemm_nt<3><<<dim3(SV/128, SV/128, HV), 256, 0, stream>>>(g);
  }

  // ---- layer 0: f_k==0 => R uniform => ex_wte/sumR == mean_v(wte) (exact) ----
  vt0_transpose_k<<<dim3(DV/32, SV/32, BV), dim3(32,8), 0, stream>>>(e, wmean, VtT);
  layer_tail0(krn, VtT, U_rs, Wo_b, f_k, f_k_b, hbuf, Gbuf, fpart,
              w1_b, w2_b, lnmw, stream);

  // ---- layer 1: PT = exp(f_k@wte^T); per-v Z and max-shift drop out of exw/colsum ----
  for (int b = 0; b < BV; b++) {
    float* partb = part + (long)b*(VV/128)*SV;
    { // PT(S,V) = exp(logits), fused partial colsum into part[b]
      GemmArgs g = {};
      g.A = f_k_b + (long)b*SV*DV; g.B = wte_b; g.Cb = PT; g.Cf = partb;
      g.K = DV; g.lda = DV; g.ldb = DV; g.ldc = VV;
      g.KC = 1;
      gemm256<5><<<dim3(SV/256, VV/256, 1), 512, 0, stream>>>(g);
    }
    { // expart[c] = partial of P'^T @ wte  (split-K=25 over V)
      GemmArgs g = {};
      g.A = PT; g.B = wteT_b; g.Cb = expart;
      g.K = VV; g.lda = VV; g.ldb = VV; g.ldc = DV;
      g.sCh = (long)SV*DV;
      g.KC = KCX;
      gemm256<7><<<dim3(SV/256, DV/256, KCX), 512, 0, stream>>>(g);
    }
    vt_part_k<<<dim3(DV/32, SV/32), dim3(32,8), 0, stream>>>(
        e + (long)b*SV*DV, expart, partb, VtT + (long)b*DV*SV);
  }

  // ---- layer-1 tail, last-row only (everything after the Wo add is row-wise
  // and only row SV-1 feeds the output logits) ----
  u_last_k<<<dim3(DV/4, HV, BV), 256, 0, stream>>>(krn, VtT, u_last);
  gemv_k<0><<<dim3(DV/4, BV), 256, 0, stream>>>(
      Wo_b + (long)1*DV*HV*DV, u_last, delta, nullptr, DV, HV*DV, (long)HV*DV);
  mid_ln_k<<<1, 128, 0, stream>>>(f_k, delta, lnmw, f_last, h_last);
  gemv_k<1><<<dim3(DFFV/4, BV), 256, 0, stream>>>(
      w1_b, h_last, nullptr, g_last, DFFV, DV, (long)DV);
  gemv_k<0><<<dim3(DV/4, BV), 256, 0, stream>>>(
      w2_b, g_last, o2buf, nullptr, DV, DFFV, (long)DFFV);
  final2_k<<<1, 128, 0, stream>>>(f_last, o2buf, lnfw, obuf);
  logits_k<<<dim3(VV/4), 256, 0, stream>>>(obuf, wte, out, VV);
}

// Round 23
// 462.767 us; speedup vs baseline: 1.0153x; 1.0153x over previous
//
#include <hip/hip_runtime.h>

#define DV   512
#define SV   1024
#define BV   2
#define VV   32000
#define HV   8
#define DFFV 2048
#define NLV  2
#define KCX  25   // exw split-K chunks (klen=1280, %32==0)

typedef __bf16 bf16;
typedef __bf16 bf16x4 __attribute__((ext_vector_type(4)));
typedef __bf16 bf16x8 __attribute__((ext_vector_type(8)));
typedef float  f32x4  __attribute__((ext_vector_type(4)));

// async global->LDS DMA, 16 B per lane; LDS dest = wave-uniform base + lane*16
__device__ __forceinline__ void lds_dma16(const void* g, void* l) {
  __builtin_amdgcn_global_load_lds(
      (const __attribute__((address_space(1))) unsigned int*)g,
      (__attribute__((address_space(3))) unsigned int*)l,
      16, 0, 0);
}

// ---------------- wave-per-row LayerNorm, D=512 ----------------
template<typename OUT>
__device__ __forceinline__ void row_ln_512(const float* __restrict__ src,
                                           const float* __restrict__ w,
                                           OUT* __restrict__ dst, int lane) {
  const float4 a = *(const float4*)(src + lane*8);
  const float4 b = *(const float4*)(src + lane*8 + 4);
  float s = a.x+a.y+a.z+a.w + b.x+b.y+b.z+b.w;
  float q = a.x*a.x+a.y*a.y+a.z*a.z+a.w*a.w + b.x*b.x+b.y*b.y+b.z*b.z+b.w*b.w;
#pragma unroll
  for (int off = 32; off > 0; off >>= 1) {
    s += __shfl_down(s, off, 64);
    q += __shfl_down(q, off, 64);
  }
  s = __shfl(s, 0, 64); q = __shfl(q, 0, 64);
  const float mu   = s * (1.0f/512.0f);
  const float rstd = rsqrtf(q * (1.0f/512.0f) - mu*mu + 1e-5f);
  const float4 wa = *(const float4*)(w + lane*8);
  const float4 wb = *(const float4*)(w + lane*8 + 4);
  OUT* d = dst + lane*8;
  d[0] = (OUT)((a.x-mu)*rstd*wa.x);
  d[1] = (OUT)((a.y-mu)*rstd*wa.y);
  d[2] = (OUT)((a.z-mu)*rstd*wa.z);
  d[3] = (OUT)((a.w-mu)*rstd*wa.w);
  d[4] = (OUT)((b.x-mu)*rstd*wb.x);
  d[5] = (OUT)((b.y-mu)*rstd*wb.y);
  d[6] = (OUT)((b.z-mu)*rstd*wb.z);
  d[7] = (OUT)((b.w-mu)*rstd*wb.w);
}

// merged: rows 0..BV*SV-1 = embedding LN (token lookup); rows BV*SV.. = wpe LN -> pn
__global__ void embed_wpe_ln_k(const int* __restrict__ x, const float* __restrict__ wte,
                               const float* __restrict__ wpe, const float* __restrict__ we,
                               const float* __restrict__ wp, float* __restrict__ e,
                               float* __restrict__ pn) {
  const int row = blockIdx.x * 4 + (threadIdx.x >> 6);
  const int lane = threadIdx.x & 63;
  if (row < BV*SV) {
    row_ln_512<float>(wte + (long)x[row] * DV, we, e + (long)row * DV, lane);
  } else {
    const int r = row - BV*SV;
    if (r >= SV + 1) return;
    row_ln_512<float>(wpe + (long)r * DV, wp, pn + (long)r * DV, lane);
  }
}

// ---------------- small prep kernels ----------------
// merged weight casts: Wo (n0), w1 (n1), w2 (n2); all sizes %4 == 0
__global__ void cast3_f2b_k(const float* __restrict__ Wo, const float* __restrict__ w1,
                            const float* __restrict__ w2, bf16* __restrict__ Wob,
                            bf16* __restrict__ w1b, bf16* __restrict__ w2b) {
  const long n0 = (long)NLV*DV*HV*DV, n1 = (long)DFFV*DV, n2 = (long)DV*DFFV;
  long i = ((long)blockIdx.x * 256 + threadIdx.x) * 4;
  const float* in; bf16* o; long r;
  if (i < n0)            { in = Wo; o = Wob; r = i; }
  else if (i < n0 + n1)  { in = w1; o = w1b; r = i - n0; }
  else if (i < n0+n1+n2) { in = w2; o = w2b; r = i - n0 - n1; }
  else return;
  const float4 v = *(const float4*)(in + r);
  bf16x4 ob; ob[0]=(bf16)v.x; ob[1]=(bf16)v.y; ob[2]=(bf16)v.z; ob[3]=(bf16)v.w;
  *(bf16x4*)(&o[r]) = ob;
}

// single-pass wte prep: read fp32 wte once, emit wte_b (cast), wteT_b (transpose-cast),
// and column-sum partials into wmean (caller pre-zeros; divide by V at use)
__global__ void wte_prep_k(const float* __restrict__ wte, bf16* __restrict__ wb,
                           bf16* __restrict__ wbT, float* __restrict__ wm) {
  __shared__ float t[32][33];
  __shared__ float cpart[8][32];
  const int d0 = blockIdx.x * 32, v0 = blockIdx.y * 32;
  const int tx = threadIdx.x, ty = threadIdx.y;
  float csum = 0.f;
#pragma unroll
  for (int k = 0; k < 4; k++) {
    const int vl = ty*4 + k;
    const float val = wte[(long)(v0+vl)*DV + d0+tx];
    t[vl][tx] = val;
    csum += val;
  }
  cpart[ty][tx] = csum;
  __syncthreads();
  const int tid = ty*32 + tx;
  const int r = tid >> 3, c = (tid & 7) * 4;
  { // vectorized cast store, same layout
    bf16x4 o;
    o[0] = (bf16)t[r][c];   o[1] = (bf16)t[r][c+1];
    o[2] = (bf16)t[r][c+2]; o[3] = (bf16)t[r][c+3];
    *(bf16x4*)(&wb[(long)(v0+r)*DV + d0+c]) = o;
  }
  { // vectorized transposed store
    bf16x4 o;
    o[0] = (bf16)t[c][r];   o[1] = (bf16)t[c+1][r];
    o[2] = (bf16)t[c+2][r]; o[3] = (bf16)t[c+3][r];
    *(bf16x4*)(&wbT[(long)(d0+r)*VV + v0+c]) = o;
  }
  if (ty == 0) {
    float s = 0.f;
#pragma unroll
    for (int k = 0; k < 8; k++) s += cpart[k][tx];
    atomicAdd(&wm[d0+tx], s);
  }
}

__global__ void qk_prep_k(const float* __restrict__ pn, const float* __restrict__ Wq,
                          const float* __restrict__ Wk, bf16* __restrict__ Qh,
                          bf16* __restrict__ Kh) {
  const int s = blockIdx.x, hh = blockIdx.y;
  const int d = threadIdx.x * 4;
  const float4 q  = *(const float4*)(pn + (long)(s+1)*DV + d);
  const float4 kk = *(const float4*)(pn + (long)s*DV + d);
  const float4 aq = *(const float4*)(Wq + (long)hh*DV + d);
  const float4 ak = *(const float4*)(Wk + (long)hh*DV + d);
  const long o = ((long)hh*SV + s)*DV + d;
  Qh[o+0]=(bf16)(q.x*aq.x);  Qh[o+1]=(bf16)(q.y*aq.y);
  Qh[o+2]=(bf16)(q.z*aq.z);  Qh[o+3]=(bf16)(q.w*aq.w);
  Kh[o+0]=(bf16)(kk.x*ak.x); Kh[o+1]=(bf16)(kk.y*ak.y);
  Kh[o+2]=(bf16)(kk.z*ak.z); Kh[o+3]=(bf16)(kk.w*ak.w);
}

// fused: f_k (+)= sum of KC slices (init=1: overwrite, skip f_k read);
// hbuf = LN(f_k) * w   (one wave per row)
__global__ void freduce_ln_k(const float* __restrict__ part, float* __restrict__ f_k,
                             const float* __restrict__ w, bf16* __restrict__ hbuf,
                             int KC, int init) {
  const int row = blockIdx.x * 4 + (threadIdx.x >> 6);
  const int lane = threadIdx.x & 63;
  const int b = row >> 10;                     // SV = 1024
  const long ro = (long)row * DV + lane*8;
  const long po = (long)(row & (SV-1)) * DV + lane*8;
  float v[8];
  if (init) {
#pragma unroll
    for (int k = 0; k < 8; k++) v[k] = 0.f;
  } else {
    const float4 a = *(const float4*)(f_k + ro);
    const float4 c = *(const float4*)(f_k + ro + 4);
    v[0]=a.x;v[1]=a.y;v[2]=a.z;v[3]=a.w;v[4]=c.x;v[5]=c.y;v[6]=c.z;v[7]=c.w;
  }
  for (int c = 0; c < KC; c++) {
    const float* pp = part + ((long)(b*KC + c))*SV*DV + po;
    const float4 a = *(const float4*)pp;
    const float4 d = *(const float4*)(pp + 4);
    v[0]+=a.x;v[1]+=a.y;v[2]+=a.z;v[3]+=a.w;v[4]+=d.x;v[5]+=d.y;v[6]+=d.z;v[7]+=d.w;
  }
  { float4 o1={v[0],v[1],v[2],v[3]}, o2={v[4],v[5],v[6],v[7]};
    *(float4*)(f_k + ro) = o1; *(float4*)(f_k + ro + 4) = o2; }
  float s = 0.f, q = 0.f;
#pragma unroll
  for (int k = 0; k < 8; k++) { s += v[k]; q += v[k]*v[k]; }
#pragma unroll
  for (int off = 32; off > 0; off >>= 1) {
    s += __shfl_down(s, off, 64);
    q += __shfl_down(q, off, 64);
  }
  s = __shfl(s, 0, 64); q = __shfl(q, 0, 64);
  const float mu   = s * (1.0f/512.0f);
  const float rstd = rsqrtf(q * (1.0f/512.0f) - mu*mu + 1e-5f);
  const float4 wa = *(const float4*)(w + lane*8);
  const float4 wb = *(const float4*)(w + lane*8 + 4);
  bf16* d = hbuf + (long)row * DV + lane*8;
  d[0] = (bf16)((v[0]-mu)*rstd*wa.x);
  d[1] = (bf16)((v[1]-mu)*rstd*wa.y);
  d[2] = (bf16)((v[2]-mu)*rstd*wa.z);
  d[3] = (bf16)((v[3]-mu)*rstd*wa.w);
  d[4] = (bf16)((v[4]-mu)*rstd*wb.x);
  d[5] = (bf16)((v[5]-mu)*rstd*wb.y);
  d[6] = (bf16)((v[6]-mu)*rstd*wb.z);
  d[7] = (bf16)((v[7]-mu)*rstd*wb.w);
}

// fused: f_k += sum of KC slices; bf16 mirror write
__global__ void freduce_cast_k(const float* __restrict__ part, float* __restrict__ f_k,
                               bf16* __restrict__ fb, int KC) {
  const long i = ((long)blockIdx.x * 256 + threadIdx.x) * 4;
  const int  b = (int)(i / ((long)SV*DV));
  const long r = i % ((long)SV*DV);
  float4 acc = *(const float4*)(f_k + i);
  for (int c = 0; c < KC; c++) {
    const float4 v = *(const float4*)(part + ((long)(b*KC + c))*SV*DV + r);
    acc.x += v.x; acc.y += v.y; acc.z += v.z; acc.w += v.w;
  }
  *(float4*)(f_k + i) = acc;
  bf16x4 o; o[0]=(bf16)acc.x; o[1]=(bf16)acc.y; o[2]=(bf16)acc.z; o[3]=(bf16)acc.w;
  *(bf16x4*)(&fb[i]) = o;
}

// Vt = e - (sum of KCX bf16 exw partial slices)/colsum, transposed (D,S) bf16 out.
// colsum computed inline from the 250 v-block partials (part is L2-resident, 1 MB).
__global__ void vt_part_k(const float* __restrict__ e, const bf16* __restrict__ pb,
                          const float* __restrict__ part, bf16* __restrict__ VtT) {
  __shared__ float t[32][33];
  __shared__ float cpart[8][32];
  __shared__ float csum[32];
  const int d0 = blockIdx.x * 32, s0 = blockIdx.y * 32;
  const int tx = threadIdx.x, ty = threadIdx.y;
  { // cooperative colsum for s0..s0+31
    float cs = 0.f;
    for (int v = ty; v < VV/128; v += 8) cs += part[(long)v * SV + s0 + tx];
    cpart[ty][tx] = cs;
  }
  __syncthreads();
  if (ty == 0) {
    float s = 0.f;
#pragma unroll
    for (int k = 0; k < 8; k++) s += cpart[k][tx];
    csum[tx] = s;
  }
  __syncthreads();
#pragma unroll
  for (int k = 0; k < 4; k++) {
    const int sl = ty + k*8;
    const long off = (long)(s0+sl)*DV + d0+tx;
    float acc = 0.f;
    for (int c = 0; c < KCX; c++) acc += (float)pb[(long)c*SV*DV + off];
    t[sl][tx] = e[off] - acc / csum[sl];
  }
  __syncthreads();
#pragma unroll
  for (int k = 0; k < 4; k++) {
    const int dl = ty + k*8;
    VtT[(long)(d0+dl)*SV + s0+tx] = (bf16)t[tx][dl];
  }
}

// layer-0 variant: ex_wte is the wte column-mean (uniform softmax), exact algebra
// (z = batch)
__global__ void vt0_transpose_k(const float* __restrict__ e, const float* __restrict__ wm,
                                bf16* __restrict__ VtT) {
  __shared__ float t[32][33];
  const int d0 = blockIdx.x * 32, s0 = blockIdx.y * 32, b = blockIdx.z;
  const int tx = threadIdx.x, ty = threadIdx.y;
  const float* eb = e + (long)b*SV*DV;
  bf16* vb = VtT + (long)b*DV*SV;
  const float mval = wm[d0 + tx] * (1.0f / (float)VV);
#pragma unroll
  for (int k = 0; k < 4; k++) {
    const int sl = ty + k*8;
    t[sl][tx] = eb[(long)(s0+sl)*DV + d0+tx] - mval;
  }
  __syncthreads();
#pragma unroll
  for (int k = 0; k < 4; k++) {
    const int dl = ty + k*8;
    vb[(long)(d0+dl)*SV + s0+tx] = (bf16)t[tx][dl];
  }
}

// ---------------- layer-1 last-row-only tail (everything after the Wo add is
// row-wise, and only row SV-1 feeds the output logits) ----------------

// U[b][h*DV+d] = dot(krn[h][SV-1][:], VtT[b][d][:])   (wave per output)
__global__ void u_last_k(const bf16* __restrict__ krn, const bf16* __restrict__ VtT,
                         bf16* __restrict__ u) {
  const int wv = threadIdx.x >> 6, lane = threadIdx.x & 63;
  const int d = blockIdx.x * 4 + wv;
  const int h = blockIdx.y, b = blockIdx.z;
  const bf16* kr = krn + (long)h*SV*SV + (long)(SV-1)*SV;
  const bf16* vr = VtT + (long)b*DV*SV + (long)d*SV;
  float acc = 0.f;
#pragma unroll
  for (int it = 0; it < 2; it++) {
    const int k = lane*8 + it*512;
    const bf16x8 a = *(const bf16x8*)(kr + k);
    const bf16x8 v = *(const bf16x8*)(vr + k);
#pragma unroll
    for (int i = 0; i < 8; i++) acc += (float)a[i] * (float)v[i];
  }
#pragma unroll
  for (int off = 32; off > 0; off >>= 1) acc += __shfl_down(acc, off, 64);
  if (lane == 0) u[((long)b*HV + h)*DV + d] = (bf16)acc;
}

// out[b][m] = act(dot(vec[b], W[m,:]))  (wave per output; W (M,K) bf16 row-major)
// ACT: 0 = none -> f32 out, 1 = gelu -> bf16 out
template<int ACT>
__global__ void gemv_k(const bf16* __restrict__ W, const bf16* __restrict__ vec,
                       float* __restrict__ outf, bf16* __restrict__ outb,
                       int M, int K, long sVb) {
  const int wv = threadIdx.x >> 6, lane = threadIdx.x & 63;
  const int m = blockIdx.x * 4 + wv;
  const int b = blockIdx.y;
  if (m >= M) return;
  const bf16* wr = W + (long)m * K;
  const bf16* vb = vec + (long)b * sVb;
  float acc = 0.f;
  for (int k = lane*8; k < K; k += 512) {
    const bf16x8 a = *(const bf16x8*)(wr + k);
    const bf16x8 v = *(const bf16x8*)(vb + k);
#pragma unroll
    for (int i = 0; i < 8; i++) acc += (float)a[i] * (float)v[i];
  }
#pragma unroll
  for (int off = 32; off > 0; off >>= 1) acc += __shfl_down(acc, off, 64);
  if (lane == 0) {
    if (ACT == 0) outf[(long)b * M + m] = acc;
    else {
      const float ge = 0.5f * acc * (1.0f + erff(acc * 0.70710678118f));
      outb[(long)b * M + m] = (bf16)ge;
    }
  }
}

// f_last = f_k[b][SV-1] + delta; h = LN(f_last) * w   (one wave per batch)
__global__ void mid_ln_k(const float* __restrict__ f_k, const float* __restrict__ delta,
                         const float* __restrict__ w, float* __restrict__ f_last,
                         bf16* __restrict__ h) {
  const int b = threadIdx.x >> 6;
  if (b >= BV) return;
  const int lane = threadIdx.x & 63;
  const long ro = ((long)b * SV + (SV - 1)) * DV + lane*8;
  const float* dp = delta + (long)b * DV + lane*8;
  float v[8];
  { const float4 a = *(const float4*)(f_k + ro);
    const float4 c = *(const float4*)(f_k + ro + 4);
    const float4 da = *(const float4*)dp;
    const float4 db = *(const float4*)(dp + 4);
    v[0]=a.x+da.x; v[1]=a.y+da.y; v[2]=a.z+da.z; v[3]=a.w+da.w;
    v[4]=c.x+db.x; v[5]=c.y+db.y; v[6]=c.z+db.z; v[7]=c.w+db.w; }
  { float* fl = f_last + (long)b*DV + lane*8;
    float4 o1={v[0],v[1],v[2],v[3]}, o2v={v[4],v[5],v[6],v[7]};
    *(float4*)fl = o1; *(float4*)(fl+4) = o2v; }
  float s = 0.f, q = 0.f;
#pragma unroll
  for (int k = 0; k < 8; k++) { s += v[k]; q += v[k]*v[k]; }
#pragma unroll
  for (int off = 32; off > 0; off >>= 1) {
    s += __shfl_down(s, off, 64);
    q += __shfl_down(q, off, 64);
  }
  s = __shfl(s, 0, 64); q = __shfl(q, 0, 64);
  const float mu   = s * (1.0f/512.0f);
  const float rstd = rsqrtf(q * (1.0f/512.0f) - mu*mu + 1e-5f);
  const float4 wa = *(const float4*)(w + lane*8);
  const float4 wb = *(const float4*)(w + lane*8 + 4);
  bf16* d = h + (long)b * DV + lane*8;
  d[0] = (bf16)((v[0]-mu)*rstd*wa.x);
  d[1] = (bf16)((v[1]-mu)*rstd*wa.y);
  d[2] = (bf16)((v[2]-mu)*rstd*wa.z);
  d[3] = (bf16)((v[3]-mu)*rstd*wa.w);
  d[4] = (bf16)((v[4]-mu)*rstd*wb.x);
  d[5] = (bf16)((v[5]-mu)*rstd*wb.y);
  d[6] = (bf16)((v[6]-mu)*rstd*wb.z);
  d[7] = (bf16)((v[7]-mu)*rstd*wb.w);
}

// obuf[b] = LN(f_last[b] + o2[b]) * w   (one wave per batch)
__global__ void final2_k(const float* __restrict__ f_last, const float* __restrict__ o2,
                         const float* __restrict__ w, float* __restrict__ obuf) {
  const int b = threadIdx.x >> 6;
  if (b >= BV) return;
  const int lane = threadIdx.x & 63;
  const float* fl = f_last + (long)b * DV + lane*8;
  const float* op = o2 + (long)b * DV + lane*8;
  float v[8];
  { const float4 a = *(const float4*)fl;
    const float4 c = *(const float4*)(fl + 4);
    const float4 da = *(const float4*)op;
    const float4 db = *(const float4*)(op + 4);
    v[0]=a.x+da.x; v[1]=a.y+da.y; v[2]=a.z+da.z; v[3]=a.w+da.w;
    v[4]=c.x+db.x; v[5]=c.y+db.y; v[6]=c.z+db.z; v[7]=c.w+db.w; }
  float s = 0.f, q = 0.f;
#pragma unroll
  for (int k = 0; k < 8; k++) { s += v[k]; q += v[k]*v[k]; }
#pragma unroll
  for (int off = 32; off > 0; off >>= 1) {
    s += __shfl_down(s, off, 64);
    q += __shfl_down(q, off, 64);
  }
  s = __shfl(s, 0, 64); q = __shfl(q, 0, 64);
  const float mu   = s * (1.0f/512.0f);
  const float rstd = rsqrtf(q * (1.0f/512.0f) - mu*mu + 1e-5f);
  const float4 wa = *(const float4*)(w + lane*8);
  const float4 wb = *(const float4*)(w + lane*8 + 4);
  float* d = obuf + (long)b * DV + lane*8;
  d[0] = (v[0]-mu)*rstd*wa.x;
  d[1] = (v[1]-mu)*rstd*wa.y;
  d[2] = (v[2]-mu)*rstd*wa.z;
  d[3] = (v[3]-mu)*rstd*wa.w;
  d[4] = (v[4]-mu)*rstd*wb.x;
  d[5] = (v[5]-mu)*rstd*wb.y;
  d[6] = (v[6]-mu)*rstd*wb.z;
  d[7] = (v[7]-mu)*rstd*wb.w;
}

// both batches in one pass over wte (fp32 kept for accuracy)
__global__ void logits_k(const float* __restrict__ obuf, const float* __restrict__ wte,
                         float* __restrict__ out, int V) {
  const int wv = threadIdx.x >> 6, lane = threadIdx.x & 63;
  const int v = blockIdx.x * 4 + wv;
  const float* wr = wte + (long)v * DV;
  const float4 a  = *(const float4*)(wr + lane*8);
  const float4 c  = *(const float4*)(wr + lane*8 + 4);
  const float4 oa0 = *(const float4*)(obuf + lane*8);
  const float4 ob0 = *(const float4*)(obuf + lane*8 + 4);
  const float4 oa1 = *(const float4*)(obuf + DV + lane*8);
  const float4 ob1 = *(const float4*)(obuf + DV + lane*8 + 4);
  float d0 = a.x*oa0.x + a.y*oa0.y + a.z*oa0.z + a.w*oa0.w
           + c.x*ob0.x + c.y*ob0.y + c.z*ob0.z + c.w*ob0.w;
  float d1 = a.x*oa1.x + a.y*oa1.y + a.z*oa1.z + a.w*oa1.w
           + c.x*ob1.x + c.y*ob1.y + c.z*ob1.z + c.w*ob1.w;
#pragma unroll
  for (int off = 32; off > 0; off >>= 1) {
    d0 += __shfl_down(d0, off, 64);
    d1 += __shfl_down(d1, off, 64);
  }
  if (lane == 0) { out[v] = d0; out[(long)V + v] = d1; }
}

// bijective XCD swizzle (m204): hw linear id -> work id, contiguous chunk per XCD
__device__ __forceinline__ long xcd_swz(long lin, long nwg) {
  const long qq = nwg >> 3, rr = nwg & 7;
  const long xcd = lin & 7, idx = lin >> 3;
  return (xcd < rr ? xcd * (qq + 1) : rr * (qq + 1) + (xcd - rr) * qq) + idx;
}

// ---------------- NT MFMA GEMM: C[m,n] = sum_k A[m,k]*B[n,k] ----------------
// 128x128x32 tile, double-buffered LDS (32 KiB total -> 4-5 blocks/CU),
// counted-vmcnt 2-phase pipeline, bijective XCD swizzle, both-sides XOR bank
// swizzle for 64 B rows: LDS[r][s] holds global slot s^((r>>1)&3).
// EPI: 2=store bf16,
//      3=causal mask * wn[m]*scale -> bf16 (krn build; fully-masked tiles skipped),
//      4=gelu -> bf16,
//      6=f32 partial-slice store (split-K, slice = b*KC+chunk, stride sCh)
struct GemmArgs {
  const bf16* A; const bf16* B;
  float* Cf; bf16* Cb;
  int K, lda, ldb, ldc;
  long sAh, sAb, sBh, sBb, sCh, sCb;
  int Hmod, KC, causal, swap;
  float scale;
};

template<int EPI>
__global__ __launch_bounds__(256)
void gemm_nt(GemmArgs g) {
  __shared__ bf16 As[2][128*32];
  __shared__ bf16 Bs[2][128*32];
  const int tid = threadIdx.x;
  int bx = blockIdx.x, by = blockIdx.y, z = blockIdx.z;
  {
    const int nbx = gridDim.x, nby = gridDim.y;
    const long nwg = (long)nbx * nby * gridDim.z;
    long lin = xcd_swz(bx + (long)nbx * (by + (long)nby * z), nwg);
    bx = (int)(lin % nbx);
    const long t2 = lin / nbx;
    by = (int)(t2 % nby);
    z  = (int)(t2 / nby);
  }
  const int chunk = z % g.KC;
  const int zo = z / g.KC;
  const int h = zo % g.Hmod;
  const int b = zo / g.Hmod;
  if (g.swap) { int t = bx; bx = by; by = t; }
  const int m0 = by * 128;
  const int n0 = bx * 128;
  const long coff = (long)h * g.sCh + (long)b * g.sCb;

  if (EPI == 3 && n0 > m0 + 127) return;  // fully-masked krn tile: never read downstream

  const bf16* A = g.A + (long)h * g.sAh + (long)b * g.sAb;
  const bf16* B = g.B + (long)h * g.sBh + (long)b * g.sBb;
  const int lane = tid & 63;
  const int wv = tid >> 6;
  const int wm = (wv >> 1) * 64;
  const int wn = (wv & 1) * 64;
  const int frow = lane & 15;
  const int quad = lane >> 4;
  const int sg8  = ((lane & 3) ^ ((lane >> 3) & 3)) * 8;
  const int drow = lane >> 2;

  const f32x4 fzero = {0.f, 0.f, 0.f, 0.f};
  f32x4 acc[4][4];
#pragma unroll
  for (int i = 0; i < 4; i++)
#pragma unroll
    for (int j = 0; j < 4; j++) acc[i][j] = fzero;

  int k0, klen;
  if (g.causal) { k0 = 0; klen = min(g.K, m0 + 128); }
  else          { klen = g.K / g.KC; k0 = chunk * klen; }

  auto stage = [&](int buf, int kk) {
#pragma unroll
    for (int c = 0; c < 2; c++) {
      const int rb = c*64 + wv*16;
      lds_dma16(A + (long)(m0 + rb + drow) * g.lda + kk + sg8, &As[buf][rb*32]);
      lds_dma16(B + (long)(n0 + rb + drow) * g.ldb + kk + sg8, &Bs[buf][rb*32]);
    }
  };

  const int nsteps = klen >> 5;  // all callers: klen % 32 == 0
  int cur = 0;
  stage(0, k0);
  for (int it = 0; it < nsteps; ++it) {
    if (it + 1 < nsteps) {
      stage(cur ^ 1, k0 + (it + 1) * 32);
      asm volatile("s_waitcnt vmcnt(4)" ::: "memory");  // cur's 4 landed, next's 4 fly
    } else {
      asm volatile("s_waitcnt vmcnt(0)" ::: "memory");
    }
    __builtin_amdgcn_s_barrier();
    bf16x8 af[4], bfr[4];
    const int sw = (frow >> 1) & 3;
#pragma unroll
    for (int i = 0; i < 4; i++)
      af[i] = *(const bf16x8*)(&As[cur][(wm + i*16 + frow)*32 + ((quad ^ sw))*8]);
#pragma unroll
    for (int j = 0; j < 4; j++)
      bfr[j] = *(const bf16x8*)(&Bs[cur][(wn + j*16 + frow)*32 + ((quad ^ sw))*8]);
#pragma unroll
    for (int i = 0; i < 4; i++)
#pragma unroll
      for (int j = 0; j < 4; j++)
        acc[i][j] = __builtin_amdgcn_mfma_f32_16x16x32_bf16(af[i], bfr[j], acc[i][j], 0, 0, 0);
    __builtin_amdgcn_s_barrier();
    cur ^= 1;
  }

  const int rb = quad * 4;
#pragma unroll
  for (int i = 0; i < 4; i++) {
#pragma unroll
    for (int j = 0; j < 4; j++) {
#pragma unroll
      for (int r = 0; r < 4; r++) {
        const int gm = m0 + wm + i*16 + rb + r;
        const int gn = n0 + wn + j*16 + frow;
        const float v = acc[i][j][r];
        if (EPI == 2) {
          g.Cb[coff + (long)gm * g.ldc + gn] = (bf16)v;
        } else if (EPI == 3) {
          const float val = (gn <= gm) ? v * g.scale / (float)(gm + 1) : 0.0f;
          g.Cb[coff + (long)gm * g.ldc + gn] = (bf16)val;
        } else if (EPI == 4) {
          const float ge = 0.5f * v * (1.0f + erff(v * 0.70710678118f));
          g.Cb[coff + (long)gm * g.ldc + gn] = (bf16)ge;
        } else if (EPI == 6) {
          g.Cf[(long)(b*g.KC + chunk) * g.sCh + (long)gm * g.ldc + gn] = v;
        }
      }
    }
  }
}

// ---------------- 256x256x32 8-wave NT GEMM, 4-buffer depth-3 pipeline --------
// r21 (BK64,2buf,depth1) and r22 (BK32,2buf,depth1) both stall-bound: one
// K-step of MFMA can't cover HBM latency, and depth-1 prefetch drains at every
// buffer swap. Fix (T3+T4, m218): 4 recyclable 16 KiB LDS units (128 KiB),
// tile t <-> buf[t&3], stage t+3 each iter, wait vmcnt(12) = tiles t+1..t+3
// in flight, tile t landed (FIFO). Never drains mid-loop; ~3 K-steps (~3200cy)
// of latency cover. Barrier pair per K-step bounds buffer recycle: stage of
// t+3 overwrites the unit released by iter t-1's closing barrier.
// T5: setprio(1) around the 32-MFMA cluster (phase-split schedule -> pays).
// Rows are 64 B = 4 x 16B slots, both-sides XOR swizzle slot^((row>>1)&3).
// m-tiles on grid x (fastest) -> B-panel sharers contiguous -> one XCD L2.
// EPI: 5 = exp -> bf16 C + per-128-col-block partial row-sums into Cf[vblk*SV+m]
//      7 = bf16 partial-slice store (split-K, slice = z, stride sCh)
template<int EPI>
__global__ __launch_bounds__(512)
void gemm256(GemmArgs g) {
  __shared__ bf16 As[4][256*32];
  __shared__ bf16 Bs[4][256*32];
  const int tid = threadIdx.x;
  int bm = blockIdx.x, bn = blockIdx.y, z = blockIdx.z;   // m fastest
  {
    const int nbx = gridDim.x, nby = gridDim.y;
    const long nwg = (long)nbx * nby * gridDim.z;
    long lin = xcd_swz(bm + (long)nbx * (bn + (long)nby * z), nwg);
    bm = (int)(lin % nbx);
    const long t2 = lin / nbx;
    bn = (int)(t2 % nby);
    z  = (int)(t2 / nby);
  }
  const int m0 = bm * 256, n0 = bn * 256;
  const int lane = tid & 63, wv = tid >> 6;
  const int wm = (wv >> 2) * 128, wn = (wv & 3) * 64;
  const int frow = lane & 15, quad = lane >> 4;
  // staging: per instr 16 rows of 64 B; lane -> (row=lane>>2, slot lane&3)
  const int sg8  = ((lane & 3) ^ ((lane >> 3) & 3)) * 8;
  const int drow = lane >> 2;

  const f32x4 fzero = {0.f, 0.f, 0.f, 0.f};
  f32x4 acc[8][4];
#pragma unroll
  for (int i = 0; i < 8; i++)
#pragma unroll
    for (int j = 0; j < 4; j++) acc[i][j] = fzero;

  const int klen = g.K / g.KC;
  const int k0 = z * klen;

  auto stage = [&](int buf, int kk) {
#pragma unroll
    for (int c = 0; c < 2; c++) {
      const int rb = c*128 + wv*16;
      lds_dma16(g.A + (long)(m0 + rb + drow) * g.lda + kk + sg8, &As[buf][rb*32]);
      lds_dma16(g.B + (long)(n0 + rb + drow) * g.ldb + kk + sg8, &Bs[buf][rb*32]);
    }
  };

  const int nsteps = klen >> 5;  // callers: klen % 32 == 0 (512, 1280)
  stage(0, k0);
  if (nsteps > 1) stage(1, k0 + 32);
  if (nsteps > 2) stage(2, k0 + 64);
  for (int it = 0; it < nsteps; ++it) {
    if (it + 3 < nsteps) {
      stage((it + 3) & 3, k0 + (it + 3) * 32);
      asm volatile("s_waitcnt vmcnt(12)" ::: "memory");  // t landed; t+1..t+3 fly
    } else if (it + 2 < nsteps) {
      asm volatile("s_waitcnt vmcnt(8)" ::: "memory");
    } else if (it + 1 < nsteps) {
      asm volatile("s_waitcnt vmcnt(4)" ::: "memory");
    } else {
      asm volatile("s_waitcnt vmcnt(0)" ::: "memory");
    }
    __builtin_amdgcn_s_barrier();   // all waves' tile-t loads landed
    const int cur = it & 3;
    const int sw = (frow >> 1) & 3;
    bf16x8 af[8], bfr[4];
#pragma unroll
    for (int j = 0; j < 4; j++)
      bfr[j] = *(const bf16x8*)(&Bs[cur][(wn + j*16 + frow)*32 + ((quad ^ sw))*8]);
#pragma unroll
    for (int i = 0; i < 8; i++)
      af[i] = *(const bf16x8*)(&As[cur][(wm + i*16 + frow)*32 + ((quad ^ sw))*8]);
    __builtin_amdgcn_s_setprio(1);
#pragma unroll
    for (int i = 0; i < 8; i++)
#pragma unroll
      for (int j = 0; j < 4; j++)
        acc[i][j] = __builtin_amdgcn_mfma_f32_16x16x32_bf16(af[i], bfr[j], acc[i][j], 0, 0, 0);
    __builtin_amdgcn_s_setprio(0);
    __builtin_amdgcn_s_barrier();   // tile-t unit released for iter t+1's stage
  }

  const int rb4 = quad * 4;
  if (EPI == 5) {
    const int vblk = (n0 + wn) >> 7;   // wave's 64-col slice lies in one 128-v block
#pragma unroll
    for (int i = 0; i < 8; i++) {
#pragma unroll
      for (int r = 0; r < 4; r++) {
        const int gm = m0 + wm + i*16 + rb4 + r;
        float rs = 0.f;
#pragma unroll
        for (int j = 0; j < 4; j++) {
          const int gn = n0 + wn + j*16 + frow;
          const float ev = __expf(acc[i][j][r]);
          g.Cb[(long)gm * g.ldc + gn] = (bf16)ev;
          rs += ev;
        }
#pragma unroll
        for (int off = 1; off < 16; off <<= 1)
          rs += __shfl_xor(rs, off, 64);
        if (frow == 0) atomicAdd(g.Cf + (long)vblk * SV + gm, rs);
      }
    }
  } else {  // EPI == 7
#pragma unroll
    for (int i = 0; i < 8; i++) {
#pragma unroll
      for (int j = 0; j < 4; j++) {
#pragma unroll
        for (int r = 0; r < 4; r++) {
          const int gm = m0 + wm + i*16 + rb4 + r;
          const int gn = n0 + wn + j*16 + frow;
          g.Cb[(long)z * g.sCh + (long)gm * g.ldc + gn] = (bf16)acc[i][j][r];
        }
      }
    }
  }
}

// layer-0 tail: U_rs -> Wo(partial+fused reduce/LN) -> MLP(partial+fused reduce+cast)
static void layer_tail0(bf16* krn, bf16* VtT, bf16* U_rs, bf16* Wo_b,
                        float* f_k, bf16* f_k_b, bf16* hbuf, bf16* Gbuf, float* fpart,
                        bf16* w1_b, bf16* w2_b, const float* lnmw, hipStream_t stream) {
  { // U_rs[b][s, h*D+d] = sum_t krn[h,s,t] * Vt[b,t,d]  (causal K-truncation)
    GemmArgs g = {};
    g.A = krn; g.B = VtT; g.Cb = U_rs;
    g.K = SV; g.lda = SV; g.ldb = SV; g.ldc = HV*DV;
    g.sAh = (long)SV*SV; g.sBb = (long)DV*SV;
    g.sCh = DV; g.sCb = (long)SV*HV*DV;
    g.Hmod = HV; g.KC = 1; g.causal = 1;
    gemm_nt<2><<<dim3(DV/128, SV/128, BV*HV), 256, 0, stream>>>(g);
  }
  { // fpart[b*8+c] = partial of U_rs @ Wo[0]^T  (split-K=8, plain stores)
    GemmArgs g = {};
    g.A = U_rs; g.B = Wo_b; g.Cf = fpart;
    g.K = HV*DV; g.lda = HV*DV; g.ldb = HV*DV; g.ldc = DV;
    g.sAb = (long)SV*HV*DV; g.sCh = (long)SV*DV;
    g.Hmod = 1; g.KC = 8; g.causal = 0;
    gemm_nt<6><<<dim3(DV/128, SV/128, BV*8), 256, 0, stream>>>(g);
  }
  freduce_ln_k<<<dim3(BV*SV/4), 256, 0, stream>>>(fpart, f_k, lnmw, hbuf, 8, 1);
  { // Gbuf = gelu(h @ w1^T)
    GemmArgs g = {};
    g.A = hbuf; g.B = w1_b; g.Cb = Gbuf;
    g.K = DV; g.lda = DV; g.ldb = DV; g.ldc = DFFV;
    g.sAb = (long)SV*DV; g.sCb = (long)SV*DFFV;
    g.Hmod = 1; g.KC = 1; g.causal = 0;
    gemm_nt<4><<<dim3(DFFV/128, SV/128, BV), 256, 0, stream>>>(g);
  }
  { // fpart[b*8+c] = partial of Gbuf @ w2^T  (split-K=8, plain stores)
    GemmArgs g = {};
    g.A = Gbuf; g.B = w2_b; g.Cf = fpart;
    g.K = DFFV; g.lda = DFFV; g.ldb = DFFV; g.ldc = DV;
    g.sAb = (long)SV*DFFV; g.sCh = (long)SV*DV;
    g.Hmod = 1; g.KC = 8; g.causal = 0;
    gemm_nt<6><<<dim3(DV/128, SV/128, BV*8), 256, 0, stream>>>(g);
  }
  freduce_cast_k<<<dim3(BV*SV*DV/4/256), 256, 0, stream>>>(fpart, f_k, f_k_b, 8);
}

extern "C" void kernel_launch(void* const* d_in, const int* in_sizes, int n_in,
                              void* d_out, int out_size, void* d_ws, size_t ws_size,
                              hipStream_t stream) {
  const int*   x    = (const int*)d_in[0];
  const float* wte  = (const float*)d_in[1];
  const float* wpe  = (const float*)d_in[2];
  const float* lnew = (const float*)d_in[3];
  const float* lnpw = (const float*)d_in[4];
  const float* lnfw = (const float*)d_in[5];
  const float* lnmw = (const float*)d_in[6];
  const float* Wq   = (const float*)d_in[7];
  const float* Wk   = (const float*)d_in[8];
  const float* Wo   = (const float*)d_in[9];
  const float* w1   = (const float*)d_in[10];
  const float* w2   = (const float*)d_in[11];
  float* out = (float*)d_out;
  (void)in_sizes; (void)n_in; (void)out_size; (void)ws_size;

  char* p = (char*)d_ws;
  auto alloc = [&](size_t bytes) -> void* {
    void* r = (void*)p;
    p += (bytes + 255) & ~(size_t)255;
    return r;
  };
  // persistent buffers (~155 MB)
  float* e      = (float*)alloc((size_t)BV*SV*DV*4);
  float* pn     = (float*)alloc((size_t)(SV+1)*DV*4);
  bf16*  wteT_b = (bf16*)alloc((size_t)DV*VV*2);
  bf16*  wte_b  = (bf16*)alloc((size_t)VV*DV*2);
  bf16*  krn    = (bf16*)alloc((size_t)HV*SV*SV*2);
  bf16*  Wo_b   = (bf16*)alloc((size_t)NLV*DV*HV*DV*2);
  bf16*  w1_b   = (bf16*)alloc((size_t)DFFV*DV*2);
  bf16*  w2_b   = (bf16*)alloc((size_t)DV*DFFV*2);
  float* f_k    = (float*)alloc((size_t)BV*SV*DV*4);
  bf16*  f_k_b  = (bf16*)alloc((size_t)BV*SV*DV*2);
  bf16*  expart = (bf16*)alloc((size_t)KCX*SV*DV*2);     // 26 MB exw bf16 partial slices
  bf16*  VtT    = (bf16*)alloc((size_t)BV*DV*SV*2);
  bf16*  hbuf   = (bf16*)alloc((size_t)BV*SV*DV*2);
  float* part   = (float*)alloc((size_t)BV*(VV/128)*SV*4); // 2 MB partial colsums [b][vblk][s]
  float* obuf   = (float*)alloc((size_t)BV*DV*4);
  float* wmean  = (float*)alloc((size_t)DV*4);
  // last-row tail buffers (tiny)
  bf16*  u_last = (bf16*)alloc((size_t)BV*HV*DV*2);
  float* delta  = (float*)alloc((size_t)BV*DV*4);
  float* f_last = (float*)alloc((size_t)BV*DV*4);
  bf16*  h_last = (bf16*)alloc((size_t)BV*DV*2);
  bf16*  g_last = (bf16*)alloc((size_t)BV*DFFV*2);
  float* o2buf  = (float*)alloc((size_t)BV*DV*4);
  // arena (65.5 MB), time-sliced: {Qh,Kh} -> tail{U_rs,Gbuf,fpart} -> PT
  char*  arena  = (char*)alloc((size_t)SV*VV*2);
  bf16*  Qh     = (bf16*)arena;
  bf16*  Kh     = (bf16*)(arena + (size_t)HV*SV*DV*2);
  bf16*  PT     = (bf16*)arena;                            // (S,V) unnormalized probs
  bf16*  U_rs   = (bf16*)arena;                            // [0, 16.8 MB)
  bf16*  Gbuf   = (bf16*)(arena + (size_t)BV*SV*HV*DV*2);  // [16.8, 25.2 MB)
  float* fpart  = (float*)(arena + (size_t)BV*SV*HV*DV*2 + (size_t)BV*SV*DFFV*2); // [25.2, 58.7)

  // ---- prologue ----
  hipMemsetAsync(wmean, 0, (size_t)DV*4, stream);
  hipMemsetAsync(part, 0, (size_t)BV*(VV/128)*SV*4, stream);
  wte_prep_k<<<dim3(DV/32, VV/32), dim3(32,8), 0, stream>>>(wte, wte_b, wteT_b, wmean);
  cast3_f2b_k<<<dim3((NLV*DV*HV*DV + DFFV*DV + DV*DFFV)/4/256), 256, 0, stream>>>(
      Wo, w1, w2, Wo_b, w1_b, w2_b);
  embed_wpe_ln_k<<<dim3((BV*SV + SV+1 + 3)/4), 256, 0, stream>>>(
      x, wte, wpe, lnew, lnpw, e, pn);
  qk_prep_k<<<dim3(SV, HV), 128, 0, stream>>>(pn, Wq, Wk, Qh, Kh);

  { // krn[h,s,t] = mask(t<=s) * (Q.K)/sqrt(D) * wn[s]  -> bf16 (masked tiles skipped)
    GemmArgs g = {};
    g.A = Qh; g.B = Kh; g.Cb = krn;
    g.K = DV; g.lda = DV; g.ldb = DV; g.ldc = SV;
    g.sAh = (long)SV*DV; g.sBh = (long)SV*DV; g.sCh = (long)SV*SV;
    g.Hmod = HV; g.KC = 1; g.causal = 0;
    g.scale = 0.044194173824159216f;  // 1/sqrt(512)
    gemm_nt<3><<<dim3(SV/128, SV/128, HV), 256, 0, stream>>>(g);
  }

  // ---- layer 0: f_k==0 => R uniform => ex_wte/sumR == mean_v(wte) (exact) ----
  vt0_transpose_k<<<dim3(DV/32, SV/32, BV), dim3(32,8), 0, stream>>>(e, wmean, VtT);
  layer_tail0(krn, VtT, U_rs, Wo_b, f_k, f_k_b, hbuf, Gbuf, fpart,
              w1_b, w2_b, lnmw, stream);

  // ---- layer 1: PT = exp(f_k@wte^T); per-v Z and max-shift drop out of exw/colsum ----
  for (int b = 0; b < BV; b++) {
    float* partb = part + (long)b*(VV/128)*SV;
    { // PT(S,V) = exp(logits), fused partial colsum into part[b]
      GemmArgs g = {};
      g.A = f_k_b + (long)b*SV*DV; g.B = wte_b; g.Cb = PT; g.Cf = partb;
      g.K = DV; g.lda = DV; g.ldb = DV; g.ldc = VV;
      g.KC = 1;
      gemm256<5><<<dim3(SV/256, VV/256, 1), 512, 0, stream>>>(g);
    }
    { // expart[c] = partial of P'^T @ wte  (split-K=25 over V)
      GemmArgs g = {};
      g.A = PT; g.B = wteT_b; g.Cb = expart;
      g.K = VV; g.lda = VV; g.ldb = VV; g.ldc = DV;
      g.sCh = (long)SV*DV;
      g.KC = KCX;
      gemm256<7><<<dim3(SV/256, DV/256, KCX), 512, 0, stream>>>(g);
    }
    vt_part_k<<<dim3(DV/32, SV/32), dim3(32,8), 0, stream>>>(
        e + (long)b*SV*DV, expart, partb, VtT + (long)b*DV*SV);
  }

  // ---- layer-1 tail, last-row only (everything after the Wo add is row-wise
  // and only row SV-1 feeds the output logits) ----
  u_last_k<<<dim3(DV/4, HV, BV), 256, 0, stream>>>(krn, VtT, u_last);
  gemv_k<0><<<dim3(DV/4, BV), 256, 0, stream>>>(
      Wo_b + (long)1*DV*HV*DV, u_last, delta, nullptr, DV, HV*DV, (long)HV*DV);
  mid_ln_k<<<1, 128, 0, stream>>>(f_k, delta, lnmw, f_last, h_last);
  gemv_k<1><<<dim3(DFFV/4, BV), 256, 0, stream>>>(
      w1_b, h_last, nullptr, g_last, DFFV, DV, (long)DV);
  gemv_k<0><<<dim3(DV/4, BV), 256, 0, stream>>>(
      w2_b, g_last, o2buf, nullptr, DV, DFFV, (long)DFFV);
  final2_k<<<1, 128, 0, stream>>>(f_last, o2buf, lnfw, obuf);
  logits_k<<<dim3(VV/4), 256, 0, stream>>>(obuf, wte, out, VV);
}

// Round 24
// 435.241 us; speedup vs baseline: 1.0795x; 1.0632x over previous
//
#include <hip/hip_runtime.h>

#define DV   512
#define SV   1024
#define BV   2
#define VV   32000
#define HV   8
#define DFFV 2048
#define NLV  2
#define KCX  25   // exw split-K chunks (klen=1280, %64==0 for 256^2 kernel)

typedef __bf16 bf16;
typedef __bf16 bf16x4 __attribute__((ext_vector_type(4)));
typedef __bf16 bf16x8 __attribute__((ext_vector_type(8)));
typedef float  f32x4  __attribute__((ext_vector_type(4)));

// async global->LDS DMA, 16 B per lane; LDS dest = wave-uniform base + lane*16
__device__ __forceinline__ void lds_dma16(const void* g, void* l) {
  __builtin_amdgcn_global_load_lds(
      (const __attribute__((address_space(1))) unsigned int*)g,
      (__attribute__((address_space(3))) unsigned int*)l,
      16, 0, 0);
}

// ---------------- wave-per-row LayerNorm, D=512 ----------------
template<typename OUT>
__device__ __forceinline__ void row_ln_512(const float* __restrict__ src,
                                           const float* __restrict__ w,
                                           OUT* __restrict__ dst, int lane) {
  const float4 a = *(const float4*)(src + lane*8);
  const float4 b = *(const float4*)(src + lane*8 + 4);
  float s = a.x+a.y+a.z+a.w + b.x+b.y+b.z+b.w;
  float q = a.x*a.x+a.y*a.y+a.z*a.z+a.w*a.w + b.x*b.x+b.y*b.y+b.z*b.z+b.w*b.w;
#pragma unroll
  for (int off = 32; off > 0; off >>= 1) {
    s += __shfl_down(s, off, 64);
    q += __shfl_down(q, off, 64);
  }
  s = __shfl(s, 0, 64); q = __shfl(q, 0, 64);
  const float mu   = s * (1.0f/512.0f);
  const float rstd = rsqrtf(q * (1.0f/512.0f) - mu*mu + 1e-5f);
  const float4 wa = *(const float4*)(w + lane*8);
  const float4 wb = *(const float4*)(w + lane*8 + 4);
  OUT* d = dst + lane*8;
  d[0] = (OUT)((a.x-mu)*rstd*wa.x);
  d[1] = (OUT)((a.y-mu)*rstd*wa.y);
  d[2] = (OUT)((a.z-mu)*rstd*wa.z);
  d[3] = (OUT)((a.w-mu)*rstd*wa.w);
  d[4] = (OUT)((b.x-mu)*rstd*wb.x);
  d[5] = (OUT)((b.y-mu)*rstd*wb.y);
  d[6] = (OUT)((b.z-mu)*rstd*wb.z);
  d[7] = (OUT)((b.w-mu)*rstd*wb.w);
}

// merged: rows 0..BV*SV-1 = embedding LN (token lookup); rows BV*SV.. = wpe LN -> pn
__global__ void embed_wpe_ln_k(const int* __restrict__ x, const float* __restrict__ wte,
                               const float* __restrict__ wpe, const float* __restrict__ we,
                               const float* __restrict__ wp, float* __restrict__ e,
                               float* __restrict__ pn) {
  const int row = blockIdx.x * 4 + (threadIdx.x >> 6);
  const int lane = threadIdx.x & 63;
  if (row < BV*SV) {
    row_ln_512<float>(wte + (long)x[row] * DV, we, e + (long)row * DV, lane);
  } else {
    const int r = row - BV*SV;
    if (r >= SV + 1) return;
    row_ln_512<float>(wpe + (long)r * DV, wp, pn + (long)r * DV, lane);
  }
}

// ---------------- small prep kernels ----------------
// merged weight casts: Wo (n0), w1 (n1), w2 (n2); all sizes %4 == 0
__global__ void cast3_f2b_k(const float* __restrict__ Wo, const float* __restrict__ w1,
                            const float* __restrict__ w2, bf16* __restrict__ Wob,
                            bf16* __restrict__ w1b, bf16* __restrict__ w2b) {
  const long n0 = (long)NLV*DV*HV*DV, n1 = (long)DFFV*DV, n2 = (long)DV*DFFV;
  long i = ((long)blockIdx.x * 256 + threadIdx.x) * 4;
  const float* in; bf16* o; long r;
  if (i < n0)            { in = Wo; o = Wob; r = i; }
  else if (i < n0 + n1)  { in = w1; o = w1b; r = i - n0; }
  else if (i < n0+n1+n2) { in = w2; o = w2b; r = i - n0 - n1; }
  else return;
  const float4 v = *(const float4*)(in + r);
  bf16x4 ob; ob[0]=(bf16)v.x; ob[1]=(bf16)v.y; ob[2]=(bf16)v.z; ob[3]=(bf16)v.w;
  *(bf16x4*)(&o[r]) = ob;
}

// single-pass wte prep: read fp32 wte once, emit wte_b (cast), wteT_b (transpose-cast),
// and column-sum partials into wmean (caller pre-zeros; divide by V at use)
__global__ void wte_prep_k(const float* __restrict__ wte, bf16* __restrict__ wb,
                           bf16* __restrict__ wbT, float* __restrict__ wm) {
  __shared__ float t[32][33];
  __shared__ float cpart[8][32];
  const int d0 = blockIdx.x * 32, v0 = blockIdx.y * 32;
  const int tx = threadIdx.x, ty = threadIdx.y;
  float csum = 0.f;
#pragma unroll
  for (int k = 0; k < 4; k++) {
    const int vl = ty*4 + k;
    const float val = wte[(long)(v0+vl)*DV + d0+tx];
    t[vl][tx] = val;
    csum += val;
  }
  cpart[ty][tx] = csum;
  __syncthreads();
  const int tid = ty*32 + tx;
  const int r = tid >> 3, c = (tid & 7) * 4;
  { // vectorized cast store, same layout
    bf16x4 o;
    o[0] = (bf16)t[r][c];   o[1] = (bf16)t[r][c+1];
    o[2] = (bf16)t[r][c+2]; o[3] = (bf16)t[r][c+3];
    *(bf16x4*)(&wb[(long)(v0+r)*DV + d0+c]) = o;
  }
  { // vectorized transposed store
    bf16x4 o;
    o[0] = (bf16)t[c][r];   o[1] = (bf16)t[c+1][r];
    o[2] = (bf16)t[c+2][r]; o[3] = (bf16)t[c+3][r];
    *(bf16x4*)(&wbT[(long)(d0+r)*VV + v0+c]) = o;
  }
  if (ty == 0) {
    float s = 0.f;
#pragma unroll
    for (int k = 0; k < 8; k++) s += cpart[k][tx];
    atomicAdd(&wm[d0+tx], s);
  }
}

__global__ void qk_prep_k(const float* __restrict__ pn, const float* __restrict__ Wq,
                          const float* __restrict__ Wk, bf16* __restrict__ Qh,
                          bf16* __restrict__ Kh) {
  const int s = blockIdx.x, hh = blockIdx.y;
  const int d = threadIdx.x * 4;
  const float4 q  = *(const float4*)(pn + (long)(s+1)*DV + d);
  const float4 kk = *(const float4*)(pn + (long)s*DV + d);
  const float4 aq = *(const float4*)(Wq + (long)hh*DV + d);
  const float4 ak = *(const float4*)(Wk + (long)hh*DV + d);
  const long o = ((long)hh*SV + s)*DV + d;
  Qh[o+0]=(bf16)(q.x*aq.x);  Qh[o+1]=(bf16)(q.y*aq.y);
  Qh[o+2]=(bf16)(q.z*aq.z);  Qh[o+3]=(bf16)(q.w*aq.w);
  Kh[o+0]=(bf16)(kk.x*ak.x); Kh[o+1]=(bf16)(kk.y*ak.y);
  Kh[o+2]=(bf16)(kk.z*ak.z); Kh[o+3]=(bf16)(kk.w*ak.w);
}

// fused: f_k (+)= sum of KC slices (init=1: overwrite, skip f_k read);
// hbuf = LN(f_k) * w   (one wave per row)
__global__ void freduce_ln_k(const float* __restrict__ part, float* __restrict__ f_k,
                             const float* __restrict__ w, bf16* __restrict__ hbuf,
                             int KC, int init) {
  const int row = blockIdx.x * 4 + (threadIdx.x >> 6);
  const int lane = threadIdx.x & 63;
  const int b = row >> 10;                     // SV = 1024
  const long ro = (long)row * DV + lane*8;
  const long po = (long)(row & (SV-1)) * DV + lane*8;
  float v[8];
  if (init) {
#pragma unroll
    for (int k = 0; k < 8; k++) v[k] = 0.f;
  } else {
    const float4 a = *(const float4*)(f_k + ro);
    const float4 c = *(const float4*)(f_k + ro + 4);
    v[0]=a.x;v[1]=a.y;v[2]=a.z;v[3]=a.w;v[4]=c.x;v[5]=c.y;v[6]=c.z;v[7]=c.w;
  }
  for (int c = 0; c < KC; c++) {
    const float* pp = part + ((long)(b*KC + c))*SV*DV + po;
    const float4 a = *(const float4*)pp;
    const float4 d = *(const float4*)(pp + 4);
    v[0]+=a.x;v[1]+=a.y;v[2]+=a.z;v[3]+=a.w;v[4]+=d.x;v[5]+=d.y;v[6]+=d.z;v[7]+=d.w;
  }
  { float4 o1={v[0],v[1],v[2],v[3]}, o2={v[4],v[5],v[6],v[7]};
    *(float4*)(f_k + ro) = o1; *(float4*)(f_k + ro + 4) = o2; }
  float s = 0.f, q = 0.f;
#pragma unroll
  for (int k = 0; k < 8; k++) { s += v[k]; q += v[k]*v[k]; }
#pragma unroll
  for (int off = 32; off > 0; off >>= 1) {
    s += __shfl_down(s, off, 64);
    q += __shfl_down(q, off, 64);
  }
  s = __shfl(s, 0, 64); q = __shfl(q, 0, 64);
  const float mu   = s * (1.0f/512.0f);
  const float rstd = rsqrtf(q * (1.0f/512.0f) - mu*mu + 1e-5f);
  const float4 wa = *(const float4*)(w + lane*8);
  const float4 wb = *(const float4*)(w + lane*8 + 4);
  bf16* d = hbuf + (long)row * DV + lane*8;
  d[0] = (bf16)((v[0]-mu)*rstd*wa.x);
  d[1] = (bf16)((v[1]-mu)*rstd*wa.y);
  d[2] = (bf16)((v[2]-mu)*rstd*wa.z);
  d[3] = (bf16)((v[3]-mu)*rstd*wa.w);
  d[4] = (bf16)((v[4]-mu)*rstd*wb.x);
  d[5] = (bf16)((v[5]-mu)*rstd*wb.y);
  d[6] = (bf16)((v[6]-mu)*rstd*wb.z);
  d[7] = (bf16)((v[7]-mu)*rstd*wb.w);
}

// fused: f_k += sum of KC slices; bf16 mirror write
__global__ void freduce_cast_k(const float* __restrict__ part, float* __restrict__ f_k,
                               bf16* __restrict__ fb, int KC) {
  const long i = ((long)blockIdx.x * 256 + threadIdx.x) * 4;
  const int  b = (int)(i / ((long)SV*DV));
  const long r = i % ((long)SV*DV);
  float4 acc = *(const float4*)(f_k + i);
  for (int c = 0; c < KC; c++) {
    const float4 v = *(const float4*)(part + ((long)(b*KC + c))*SV*DV + r);
    acc.x += v.x; acc.y += v.y; acc.z += v.z; acc.w += v.w;
  }
  *(float4*)(f_k + i) = acc;
  bf16x4 o; o[0]=(bf16)acc.x; o[1]=(bf16)acc.y; o[2]=(bf16)acc.z; o[3]=(bf16)acc.w;
  *(bf16x4*)(&fb[i]) = o;
}

// Vt = e - (sum of KCX bf16 exw partial slices)/colsum, transposed (D,S) bf16 out.
// colsum computed inline from the 250 v-block partials (part is L2-resident, 1 MB).
__global__ void vt_part_k(const float* __restrict__ e, const bf16* __restrict__ pb,
                          const float* __restrict__ part, bf16* __restrict__ VtT) {
  __shared__ float t[32][33];
  __shared__ float cpart[8][32];
  __shared__ float csum[32];
  const int d0 = blockIdx.x * 32, s0 = blockIdx.y * 32;
  const int tx = threadIdx.x, ty = threadIdx.y;
  { // cooperative colsum for s0..s0+31
    float cs = 0.f;
    for (int v = ty; v < VV/128; v += 8) cs += part[(long)v * SV + s0 + tx];
    cpart[ty][tx] = cs;
  }
  __syncthreads();
  if (ty == 0) {
    float s = 0.f;
#pragma unroll
    for (int k = 0; k < 8; k++) s += cpart[k][tx];
    csum[tx] = s;
  }
  __syncthreads();
#pragma unroll
  for (int k = 0; k < 4; k++) {
    const int sl = ty + k*8;
    const long off = (long)(s0+sl)*DV + d0+tx;
    float acc = 0.f;
    for (int c = 0; c < KCX; c++) acc += (float)pb[(long)c*SV*DV + off];
    t[sl][tx] = e[off] - acc / csum[sl];
  }
  __syncthreads();
#pragma unroll
  for (int k = 0; k < 4; k++) {
    const int dl = ty + k*8;
    VtT[(long)(d0+dl)*SV + s0+tx] = (bf16)t[tx][dl];
  }
}

// layer-0 variant: ex_wte is the wte column-mean (uniform softmax), exact algebra
// (z = batch)
__global__ void vt0_transpose_k(const float* __restrict__ e, const float* __restrict__ wm,
                                bf16* __restrict__ VtT) {
  __shared__ float t[32][33];
  const int d0 = blockIdx.x * 32, s0 = blockIdx.y * 32, b = blockIdx.z;
  const int tx = threadIdx.x, ty = threadIdx.y;
  const float* eb = e + (long)b*SV*DV;
  bf16* vb = VtT + (long)b*DV*SV;
  const float mval = wm[d0 + tx] * (1.0f / (float)VV);
#pragma unroll
  for (int k = 0; k < 4; k++) {
    const int sl = ty + k*8;
    t[sl][tx] = eb[(long)(s0+sl)*DV + d0+tx] - mval;
  }
  __syncthreads();
#pragma unroll
  for (int k = 0; k < 4; k++) {
    const int dl = ty + k*8;
    vb[(long)(d0+dl)*SV + s0+tx] = (bf16)t[tx][dl];
  }
}

// ---------------- layer-1 last-row-only tail (everything after the Wo add is
// row-wise, and only row SV-1 feeds the output logits) ----------------

// U[b][h*DV+d] = dot(krn[h][SV-1][:], VtT[b][d][:])   (wave per output)
__global__ void u_last_k(const bf16* __restrict__ krn, const bf16* __restrict__ VtT,
                         bf16* __restrict__ u) {
  const int wv = threadIdx.x >> 6, lane = threadIdx.x & 63;
  const int d = blockIdx.x * 4 + wv;
  const int h = blockIdx.y, b = blockIdx.z;
  const bf16* kr = krn + (long)h*SV*SV + (long)(SV-1)*SV;
  const bf16* vr = VtT + (long)b*DV*SV + (long)d*SV;
  float acc = 0.f;
#pragma unroll
  for (int it = 0; it < 2; it++) {
    const int k = lane*8 + it*512;
    const bf16x8 a = *(const bf16x8*)(kr + k);
    const bf16x8 v = *(const bf16x8*)(vr + k);
#pragma unroll
    for (int i = 0; i < 8; i++) acc += (float)a[i] * (float)v[i];
  }
#pragma unroll
  for (int off = 32; off > 0; off >>= 1) acc += __shfl_down(acc, off, 64);
  if (lane == 0) u[((long)b*HV + h)*DV + d] = (bf16)acc;
}

// out[b][m] = act(dot(vec[b], W[m,:]))  (wave per output; W (M,K) bf16 row-major)
// ACT: 0 = none -> f32 out, 1 = gelu -> bf16 out
template<int ACT>
__global__ void gemv_k(const bf16* __restrict__ W, const bf16* __restrict__ vec,
                       float* __restrict__ outf, bf16* __restrict__ outb,
                       int M, int K, long sVb) {
  const int wv = threadIdx.x >> 6, lane = threadIdx.x & 63;
  const int m = blockIdx.x * 4 + wv;
  const int b = blockIdx.y;
  if (m >= M) return;
  const bf16* wr = W + (long)m * K;
  const bf16* vb = vec + (long)b * sVb;
  float acc = 0.f;
  for (int k = lane*8; k < K; k += 512) {
    const bf16x8 a = *(const bf16x8*)(wr + k);
    const bf16x8 v = *(const bf16x8*)(vb + k);
#pragma unroll
    for (int i = 0; i < 8; i++) acc += (float)a[i] * (float)v[i];
  }
#pragma unroll
  for (int off = 32; off > 0; off >>= 1) acc += __shfl_down(acc, off, 64);
  if (lane == 0) {
    if (ACT == 0) outf[(long)b * M + m] = acc;
    else {
      const float ge = 0.5f * acc * (1.0f + erff(acc * 0.70710678118f));
      outb[(long)b * M + m] = (bf16)ge;
    }
  }
}

// f_last = f_k[b][SV-1] + delta; h = LN(f_last) * w   (one wave per batch)
__global__ void mid_ln_k(const float* __restrict__ f_k, const float* __restrict__ delta,
                         const float* __restrict__ w, float* __restrict__ f_last,
                         bf16* __restrict__ h) {
  const int b = threadIdx.x >> 6;
  if (b >= BV) return;
  const int lane = threadIdx.x & 63;
  const long ro = ((long)b * SV + (SV - 1)) * DV + lane*8;
  const float* dp = delta + (long)b * DV + lane*8;
  float v[8];
  { const float4 a = *(const float4*)(f_k + ro);
    const float4 c = *(const float4*)(f_k + ro + 4);
    const float4 da = *(const float4*)dp;
    const float4 db = *(const float4*)(dp + 4);
    v[0]=a.x+da.x; v[1]=a.y+da.y; v[2]=a.z+da.z; v[3]=a.w+da.w;
    v[4]=c.x+db.x; v[5]=c.y+db.y; v[6]=c.z+db.z; v[7]=c.w+db.w; }
  { float* fl = f_last + (long)b*DV + lane*8;
    float4 o1={v[0],v[1],v[2],v[3]}, o2v={v[4],v[5],v[6],v[7]};
    *(float4*)fl = o1; *(float4*)(fl+4) = o2v; }
  float s = 0.f, q = 0.f;
#pragma unroll
  for (int k = 0; k < 8; k++) { s += v[k]; q += v[k]*v[k]; }
#pragma unroll
  for (int off = 32; off > 0; off >>= 1) {
    s += __shfl_down(s, off, 64);
    q += __shfl_down(q, off, 64);
  }
  s = __shfl(s, 0, 64); q = __shfl(q, 0, 64);
  const float mu   = s * (1.0f/512.0f);
  const float rstd = rsqrtf(q * (1.0f/512.0f) - mu*mu + 1e-5f);
  const float4 wa = *(const float4*)(w + lane*8);
  const float4 wb = *(const float4*)(w + lane*8 + 4);
  bf16* d = h + (long)b * DV + lane*8;
  d[0] = (bf16)((v[0]-mu)*rstd*wa.x);
  d[1] = (bf16)((v[1]-mu)*rstd*wa.y);
  d[2] = (bf16)((v[2]-mu)*rstd*wa.z);
  d[3] = (bf16)((v[3]-mu)*rstd*wa.w);
  d[4] = (bf16)((v[4]-mu)*rstd*wb.x);
  d[5] = (bf16)((v[5]-mu)*rstd*wb.y);
  d[6] = (bf16)((v[6]-mu)*rstd*wb.z);
  d[7] = (bf16)((v[7]-mu)*rstd*wb.w);
}

// obuf[b] = LN(f_last[b] + o2[b]) * w   (one wave per batch)
__global__ void final2_k(const float* __restrict__ f_last, const float* __restrict__ o2,
                         const float* __restrict__ w, float* __restrict__ obuf) {
  const int b = threadIdx.x >> 6;
  if (b >= BV) return;
  const int lane = threadIdx.x & 63;
  const float* fl = f_last + (long)b * DV + lane*8;
  const float* op = o2 + (long)b * DV + lane*8;
  float v[8];
  { const float4 a = *(const float4*)fl;
    const float4 c = *(const float4*)(fl + 4);
    const float4 da = *(const float4*)op;
    const float4 db = *(const float4*)(op + 4);
    v[0]=a.x+da.x; v[1]=a.y+da.y; v[2]=a.z+da.z; v[3]=a.w+da.w;
    v[4]=c.x+db.x; v[5]=c.y+db.y; v[6]=c.z+db.z; v[7]=c.w+db.w; }
  float s = 0.f, q = 0.f;
#pragma unroll
  for (int k = 0; k < 8; k++) { s += v[k]; q += v[k]*v[k]; }
#pragma unroll
  for (int off = 32; off > 0; off >>= 1) {
    s += __shfl_down(s, off, 64);
    q += __shfl_down(q, off, 64);
  }
  s = __shfl(s, 0, 64); q = __shfl(q, 0, 64);
  const float mu   = s * (1.0f/512.0f);
  const float rstd = rsqrtf(q * (1.0f/512.0f) - mu*mu + 1e-5f);
  const float4 wa = *(const float4*)(w + lane*8);
  const float4 wb = *(const float4*)(w + lane*8 + 4);
  float* d = obuf + (long)b * DV + lane*8;
  d[0] = (v[0]-mu)*rstd*wa.x;
  d[1] = (v[1]-mu)*rstd*wa.y;
  d[2] = (v[2]-mu)*rstd*wa.z;
  d[3] = (v[3]-mu)*rstd*wa.w;
  d[4] = (v[4]-mu)*rstd*wb.x;
  d[5] = (v[5]-mu)*rstd*wb.y;
  d[6] = (v[6]-mu)*rstd*wb.z;
  d[7] = (v[7]-mu)*rstd*wb.w;
}

// both batches in one pass over wte (fp32 kept for accuracy)
__global__ void logits_k(const float* __restrict__ obuf, const float* __restrict__ wte,
                         float* __restrict__ out, int V) {
  const int wv = threadIdx.x >> 6, lane = threadIdx.x & 63;
  const int v = blockIdx.x * 4 + wv;
  const float* wr = wte + (long)v * DV;
  const float4 a  = *(const float4*)(wr + lane*8);
  const float4 c  = *(const float4*)(wr + lane*8 + 4);
  const float4 oa0 = *(const float4*)(obuf + lane*8);
  const float4 ob0 = *(const float4*)(obuf + lane*8 + 4);
  const float4 oa1 = *(const float4*)(obuf + DV + lane*8);
  const float4 ob1 = *(const float4*)(obuf + DV + lane*8 + 4);
  float d0 = a.x*oa0.x + a.y*oa0.y + a.z*oa0.z + a.w*oa0.w
           + c.x*ob0.x + c.y*ob0.y + c.z*ob0.z + c.w*ob0.w;
  float d1 = a.x*oa1.x + a.y*oa1.y + a.z*oa1.z + a.w*oa1.w
           + c.x*ob1.x + c.y*ob1.y + c.z*ob1.z + c.w*ob1.w;
#pragma unroll
  for (int off = 32; off > 0; off >>= 1) {
    d0 += __shfl_down(d0, off, 64);
    d1 += __shfl_down(d1, off, 64);
  }
  if (lane == 0) { out[v] = d0; out[(long)V + v] = d1; }
}

// bijective XCD swizzle (m204): hw linear id -> work id, contiguous chunk per XCD
__device__ __forceinline__ long xcd_swz(long lin, long nwg) {
  const long qq = nwg >> 3, rr = nwg & 7;
  const long xcd = lin & 7, idx = lin >> 3;
  return (xcd < rr ? xcd * (qq + 1) : rr * (qq + 1) + (xcd - rr) * qq) + idx;
}

// ---------------- NT MFMA GEMM: C[m,n] = sum_k A[m,k]*B[n,k] ----------------
// 128x128x32 tile, double-buffered LDS (32 KiB total -> 4-5 blocks/CU),
// counted-vmcnt 2-phase pipeline, bijective XCD swizzle, both-sides XOR bank
// swizzle for 64 B rows: LDS[r][s] holds global slot s^((r>>1)&3).
// EPI: 2=store bf16,
//      3=causal mask * wn[m]*scale -> bf16 (krn build; fully-masked tiles skipped),
//      4=gelu -> bf16,
//      6=f32 partial-slice store (split-K, slice = b*KC+chunk, stride sCh)
struct GemmArgs {
  const bf16* A; const bf16* B;
  float* Cf; bf16* Cb;
  int K, lda, ldb, ldc;
  long sAh, sAb, sBh, sBb, sCh, sCb;
  int Hmod, KC, causal, swap;
  float scale;
};

template<int EPI>
__global__ __launch_bounds__(256)
void gemm_nt(GemmArgs g) {
  __shared__ bf16 As[2][128*32];
  __shared__ bf16 Bs[2][128*32];
  const int tid = threadIdx.x;
  int bx = blockIdx.x, by = blockIdx.y, z = blockIdx.z;
  {
    const int nbx = gridDim.x, nby = gridDim.y;
    const long nwg = (long)nbx * nby * gridDim.z;
    long lin = xcd_swz(bx + (long)nbx * (by + (long)nby * z), nwg);
    bx = (int)(lin % nbx);
    const long t2 = lin / nbx;
    by = (int)(t2 % nby);
    z  = (int)(t2 / nby);
  }
  const int chunk = z % g.KC;
  const int zo = z / g.KC;
  const int h = zo % g.Hmod;
  const int b = zo / g.Hmod;
  if (g.swap) { int t = bx; bx = by; by = t; }
  const int m0 = by * 128;
  const int n0 = bx * 128;
  const long coff = (long)h * g.sCh + (long)b * g.sCb;

  if (EPI == 3 && n0 > m0 + 127) return;  // fully-masked krn tile: never read downstream

  const bf16* A = g.A + (long)h * g.sAh + (long)b * g.sAb;
  const bf16* B = g.B + (long)h * g.sBh + (long)b * g.sBb;
  const int lane = tid & 63;
  const int wv = tid >> 6;
  const int wm = (wv >> 1) * 64;
  const int wn = (wv & 1) * 64;
  const int frow = lane & 15;
  const int quad = lane >> 4;
  const int sg8  = ((lane & 3) ^ ((lane >> 3) & 3)) * 8;
  const int drow = lane >> 2;

  const f32x4 fzero = {0.f, 0.f, 0.f, 0.f};
  f32x4 acc[4][4];
#pragma unroll
  for (int i = 0; i < 4; i++)
#pragma unroll
    for (int j = 0; j < 4; j++) acc[i][j] = fzero;

  int k0, klen;
  if (g.causal) { k0 = 0; klen = min(g.K, m0 + 128); }
  else          { klen = g.K / g.KC; k0 = chunk * klen; }

  auto stage = [&](int buf, int kk) {
#pragma unroll
    for (int c = 0; c < 2; c++) {
      const int rb = c*64 + wv*16;
      lds_dma16(A + (long)(m0 + rb + drow) * g.lda + kk + sg8, &As[buf][rb*32]);
      lds_dma16(B + (long)(n0 + rb + drow) * g.ldb + kk + sg8, &Bs[buf][rb*32]);
    }
  };

  const int nsteps = klen >> 5;  // all callers: klen % 32 == 0
  int cur = 0;
  stage(0, k0);
  for (int it = 0; it < nsteps; ++it) {
    if (it + 1 < nsteps) {
      stage(cur ^ 1, k0 + (it + 1) * 32);
      asm volatile("s_waitcnt vmcnt(4)" ::: "memory");  // cur's 4 landed, next's 4 fly
    } else {
      asm volatile("s_waitcnt vmcnt(0)" ::: "memory");
    }
    __builtin_amdgcn_s_barrier();
    bf16x8 af[4], bfr[4];
    const int sw = (frow >> 1) & 3;
#pragma unroll
    for (int i = 0; i < 4; i++)
      af[i] = *(const bf16x8*)(&As[cur][(wm + i*16 + frow)*32 + ((quad ^ sw))*8]);
#pragma unroll
    for (int j = 0; j < 4; j++)
      bfr[j] = *(const bf16x8*)(&Bs[cur][(wn + j*16 + frow)*32 + ((quad ^ sw))*8]);
#pragma unroll
    for (int i = 0; i < 4; i++)
#pragma unroll
      for (int j = 0; j < 4; j++)
        acc[i][j] = __builtin_amdgcn_mfma_f32_16x16x32_bf16(af[i], bfr[j], acc[i][j], 0, 0, 0);
    __builtin_amdgcn_s_barrier();
    cur ^= 1;
  }

  const int rb = quad * 4;
#pragma unroll
  for (int i = 0; i < 4; i++) {
#pragma unroll
    for (int j = 0; j < 4; j++) {
#pragma unroll
      for (int r = 0; r < 4; r++) {
        const int gm = m0 + wm + i*16 + rb + r;
        const int gn = n0 + wn + j*16 + frow;
        const float v = acc[i][j][r];
        if (EPI == 2) {
          g.Cb[coff + (long)gm * g.ldc + gn] = (bf16)v;
        } else if (EPI == 3) {
          const float val = (gn <= gm) ? v * g.scale / (float)(gm + 1) : 0.0f;
          g.Cb[coff + (long)gm * g.ldc + gn] = (bf16)val;
        } else if (EPI == 4) {
          const float ge = 0.5f * v * (1.0f + erff(v * 0.70710678118f));
          g.Cb[coff + (long)gm * g.ldc + gn] = (bf16)ge;
        } else if (EPI == 6) {
          g.Cf[(long)(b*g.KC + chunk) * g.sCh + (long)gm * g.ldc + gn] = v;
        }
      }
    }
  }
}

// ---------------- 256x256x64 8-wave NT GEMM (session-best schedule) ------------
// BK=64, double-buffered LDS (128 KiB), counted-vmcnt 2-phase pipeline.
// Grid: m-tiles on x (FASTEST) -> B-panel sharers contiguous -> one XCD L2.
// Rows are 128 B = 8 x 16B slots, both-sides XOR swizzle slot^(row&7): 0 bank
// conflicts. Direct-store epilogue.
// Schedule note (r22/r23): BK32 variants (depth-1 and depth-3) both regress to
// ~67 us vs this BK64 depth-1 at ~60 us -- barrier amortization dominates
// prefetch depth at this K-scale; the 2-barrier-per-K-step structure is the
// measured plateau (cf. m233).
// EPI: 5 = exp -> bf16 C + per-128-col-block partial row-sums into Cf[vblk*SV+m]
//      7 = bf16 partial-slice store (split-K, slice = z, stride sCh)
template<int EPI>
__global__ __launch_bounds__(512)
void gemm256(GemmArgs g) {
  __shared__ bf16 As[2][256*64];
  __shared__ bf16 Bs[2][256*64];
  const int tid = threadIdx.x;
  int bm = blockIdx.x, bn = blockIdx.y, z = blockIdx.z;   // m fastest
  {
    const int nbx = gridDim.x, nby = gridDim.y;
    const long nwg = (long)nbx * nby * gridDim.z;
    long lin = xcd_swz(bm + (long)nbx * (bn + (long)nby * z), nwg);
    bm = (int)(lin % nbx);
    const long t2 = lin / nbx;
    bn = (int)(t2 % nby);
    z  = (int)(t2 / nby);
  }
  const int m0 = bm * 256, n0 = bn * 256;
  const int lane = tid & 63, wv = tid >> 6;
  const int wm = (wv >> 2) * 128, wn = (wv & 3) * 64;
  const int frow = lane & 15, quad = lane >> 4;
  // staging: per instr 8 rows of 128 B; lane -> (row=lane>>3, slot lane&7)
  const int sg8  = ((lane & 7) ^ (lane >> 3)) * 8;
  const int drow = lane >> 3;

  const f32x4 fzero = {0.f, 0.f, 0.f, 0.f};
  f32x4 acc[8][4];
#pragma unroll
  for (int i = 0; i < 8; i++)
#pragma unroll
    for (int j = 0; j < 4; j++) acc[i][j] = fzero;

  const int klen = g.K / g.KC;
  const int k0 = z * klen;

  auto stage = [&](int buf, int kk) {
#pragma unroll
    for (int c = 0; c < 4; c++) {
      const int rb = c*64 + wv*8;
      lds_dma16(g.A + (long)(m0 + rb + drow) * g.lda + kk + sg8, &As[buf][rb*64]);
      lds_dma16(g.B + (long)(n0 + rb + drow) * g.ldb + kk + sg8, &Bs[buf][rb*64]);
    }
  };

  const int nsteps = klen >> 6;  // callers: klen % 64 == 0
  int cur = 0;
  stage(0, k0);
  for (int it = 0; it < nsteps; ++it) {
    if (it + 1 < nsteps) {
      stage(cur ^ 1, k0 + (it + 1) * 64);
      asm volatile("s_waitcnt vmcnt(8)" ::: "memory");  // cur's 8 landed, next's 8 fly
    } else {
      asm volatile("s_waitcnt vmcnt(0)" ::: "memory");
    }
    __builtin_amdgcn_s_barrier();
    const int sw = frow & 7;
#pragma unroll
    for (int ks = 0; ks < 2; ks++) {
      bf16x8 af[8], bfr[4];
#pragma unroll
      for (int j = 0; j < 4; j++)
        bfr[j] = *(const bf16x8*)(&Bs[cur][(wn + j*16 + frow)*64 + (((ks*4 + quad) ^ sw))*8]);
#pragma unroll
      for (int i = 0; i < 8; i++)
        af[i] = *(const bf16x8*)(&As[cur][(wm + i*16 + frow)*64 + (((ks*4 + quad) ^ sw))*8]);
#pragma unroll
      for (int i = 0; i < 8; i++)
#pragma unroll
        for (int j = 0; j < 4; j++)
          acc[i][j] = __builtin_amdgcn_mfma_f32_16x16x32_bf16(af[i], bfr[j], acc[i][j], 0, 0, 0);
    }
    __builtin_amdgcn_s_barrier();
    cur ^= 1;
  }

  const int rb4 = quad * 4;
  if (EPI == 5) {
    const int vblk = (n0 + wn) >> 7;   // wave's 64-col slice lies in one 128-v block
#pragma unroll
    for (int i = 0; i < 8; i++) {
#pragma unroll
      for (int r = 0; r < 4; r++) {
        const int gm = m0 + wm + i*16 + rb4 + r;
        float rs = 0.f;
#pragma unroll
        for (int j = 0; j < 4; j++) {
          const int gn = n0 + wn + j*16 + frow;
          const float ev = __expf(acc[i][j][r]);
          g.Cb[(long)gm * g.ldc + gn] = (bf16)ev;
          rs += ev;
        }
#pragma unroll
        for (int off = 1; off < 16; off <<= 1)
          rs += __shfl_xor(rs, off, 64);
        if (frow == 0) atomicAdd(g.Cf + (long)vblk * SV + gm, rs);
      }
    }
  } else {  // EPI == 7
#pragma unroll
    for (int i = 0; i < 8; i++) {
#pragma unroll
      for (int j = 0; j < 4; j++) {
#pragma unroll
        for (int r = 0; r < 4; r++) {
          const int gm = m0 + wm + i*16 + rb4 + r;
          const int gn = n0 + wn + j*16 + frow;
          g.Cb[(long)z * g.sCh + (long)gm * g.ldc + gn] = (bf16)acc[i][j][r];
        }
      }
    }
  }
}

// layer-0 tail: U_rs -> Wo(partial+fused reduce/LN) -> MLP(partial+fused reduce+cast)
static void layer_tail0(bf16* krn, bf16* VtT, bf16* U_rs, bf16* Wo_b,
                        float* f_k, bf16* f_k_b, bf16* hbuf, bf16* Gbuf, float* fpart,
                        bf16* w1_b, bf16* w2_b, const float* lnmw, hipStream_t stream) {
  { // U_rs[b][s, h*D+d] = sum_t krn[h,s,t] * Vt[b,t,d]  (causal K-truncation)
    GemmArgs g = {};
    g.A = krn; g.B = VtT; g.Cb = U_rs;
    g.K = SV; g.lda = SV; g.ldb = SV; g.ldc = HV*DV;
    g.sAh = (long)SV*SV; g.sBb = (long)DV*SV;
    g.sCh = DV; g.sCb = (long)SV*HV*DV;
    g.Hmod = HV; g.KC = 1; g.causal = 1;
    gemm_nt<2><<<dim3(DV/128, SV/128, BV*HV), 256, 0, stream>>>(g);
  }
  { // fpart[b*8+c] = partial of U_rs @ Wo[0]^T  (split-K=8, plain stores)
    GemmArgs g = {};
    g.A = U_rs; g.B = Wo_b; g.Cf = fpart;
    g.K = HV*DV; g.lda = HV*DV; g.ldb = HV*DV; g.ldc = DV;
    g.sAb = (long)SV*HV*DV; g.sCh = (long)SV*DV;
    g.Hmod = 1; g.KC = 8; g.causal = 0;
    gemm_nt<6><<<dim3(DV/128, SV/128, BV*8), 256, 0, stream>>>(g);
  }
  freduce_ln_k<<<dim3(BV*SV/4), 256, 0, stream>>>(fpart, f_k, lnmw, hbuf, 8, 1);
  { // Gbuf = gelu(h @ w1^T)
    GemmArgs g = {};
    g.A = hbuf; g.B = w1_b; g.Cb = Gbuf;
    g.K = DV; g.lda = DV; g.ldb = DV; g.ldc = DFFV;
    g.sAb = (long)SV*DV; g.sCb = (long)SV*DFFV;
    g.Hmod = 1; g.KC = 1; g.causal = 0;
    gemm_nt<4><<<dim3(DFFV/128, SV/128, BV), 256, 0, stream>>>(g);
  }
  { // fpart[b*8+c] = partial of Gbuf @ w2^T  (split-K=8, plain stores)
    GemmArgs g = {};
    g.A = Gbuf; g.B = w2_b; g.Cf = fpart;
    g.K = DFFV; g.lda = DFFV; g.ldb = DFFV; g.ldc = DV;
    g.sAb = (long)SV*DFFV; g.sCh = (long)SV*DV;
    g.Hmod = 1; g.KC = 8; g.causal = 0;
    gemm_nt<6><<<dim3(DV/128, SV/128, BV*8), 256, 0, stream>>>(g);
  }
  freduce_cast_k<<<dim3(BV*SV*DV/4/256), 256, 0, stream>>>(fpart, f_k, f_k_b, 8);
}

extern "C" void kernel_launch(void* const* d_in, const int* in_sizes, int n_in,
                              void* d_out, int out_size, void* d_ws, size_t ws_size,
                              hipStream_t stream) {
  const int*   x    = (const int*)d_in[0];
  const float* wte  = (const float*)d_in[1];
  const float* wpe  = (const float*)d_in[2];
  const float* lnew = (const float*)d_in[3];
  const float* lnpw = (const float*)d_in[4];
  const float* lnfw = (const float*)d_in[5];
  const float* lnmw = (const float*)d_in[6];
  const float* Wq   = (const float*)d_in[7];
  const float* Wk   = (const float*)d_in[8];
  const float* Wo   = (const float*)d_in[9];
  const float* w1   = (const float*)d_in[10];
  const float* w2   = (const float*)d_in[11];
  float* out = (float*)d_out;
  (void)in_sizes; (void)n_in; (void)out_size; (void)ws_size;

  char* p = (char*)d_ws;
  auto alloc = [&](size_t bytes) -> void* {
    void* r = (void*)p;
    p += (bytes + 255) & ~(size_t)255;
    return r;
  };
  // persistent buffers (~155 MB)
  float* e      = (float*)alloc((size_t)BV*SV*DV*4);
  float* pn     = (float*)alloc((size_t)(SV+1)*DV*4);
  bf16*  wteT_b = (bf16*)alloc((size_t)DV*VV*2);
  bf16*  wte_b  = (bf16*)alloc((size_t)VV*DV*2);
  bf16*  krn    = (bf16*)alloc((size_t)HV*SV*SV*2);
  bf16*  Wo_b   = (bf16*)alloc((size_t)NLV*DV*HV*DV*2);
  bf16*  w1_b   = (bf16*)alloc((size_t)DFFV*DV*2);
  bf16*  w2_b   = (bf16*)alloc((size_t)DV*DFFV*2);
  float* f_k    = (float*)alloc((size_t)BV*SV*DV*4);
  bf16*  f_k_b  = (bf16*)alloc((size_t)BV*SV*DV*2);
  bf16*  expart = (bf16*)alloc((size_t)KCX*SV*DV*2);     // 26 MB exw bf16 partial slices
  bf16*  VtT    = (bf16*)alloc((size_t)BV*DV*SV*2);
  bf16*  hbuf   = (bf16*)alloc((size_t)BV*SV*DV*2);
  float* part   = (float*)alloc((size_t)BV*(VV/128)*SV*4); // 2 MB partial colsums [b][vblk][s]
  float* obuf   = (float*)alloc((size_t)BV*DV*4);
  float* wmean  = (float*)alloc((size_t)DV*4);
  // last-row tail buffers (tiny)
  bf16*  u_last = (bf16*)alloc((size_t)BV*HV*DV*2);
  float* delta  = (float*)alloc((size_t)BV*DV*4);
  float* f_last = (float*)alloc((size_t)BV*DV*4);
  bf16*  h_last = (bf16*)alloc((size_t)BV*DV*2);
  bf16*  g_last = (bf16*)alloc((size_t)BV*DFFV*2);
  float* o2buf  = (float*)alloc((size_t)BV*DV*4);
  // arena (65.5 MB), time-sliced: {Qh,Kh} -> tail{U_rs,Gbuf,fpart} -> PT
  char*  arena  = (char*)alloc((size_t)SV*VV*2);
  bf16*  Qh     = (bf16*)arena;
  bf16*  Kh     = (bf16*)(arena + (size_t)HV*SV*DV*2);
  bf16*  PT     = (bf16*)arena;                            // (S,V) unnormalized probs
  bf16*  U_rs   = (bf16*)arena;                            // [0, 16.8 MB)
  bf16*  Gbuf   = (bf16*)(arena + (size_t)BV*SV*HV*DV*2);  // [16.8, 25.2 MB)
  float* fpart  = (float*)(arena + (size_t)BV*SV*HV*DV*2 + (size_t)BV*SV*DFFV*2); // [25.2, 58.7)

  // ---- prologue ----
  hipMemsetAsync(wmean, 0, (size_t)DV*4, stream);
  hipMemsetAsync(part, 0, (size_t)BV*(VV/128)*SV*4, stream);
  wte_prep_k<<<dim3(DV/32, VV/32), dim3(32,8), 0, stream>>>(wte, wte_b, wteT_b, wmean);
  cast3_f2b_k<<<dim3((NLV*DV*HV*DV + DFFV*DV + DV*DFFV)/4/256), 256, 0, stream>>>(
      Wo, w1, w2, Wo_b, w1_b, w2_b);
  embed_wpe_ln_k<<<dim3((BV*SV + SV+1 + 3)/4), 256, 0, stream>>>(
      x, wte, wpe, lnew, lnpw, e, pn);
  qk_prep_k<<<dim3(SV, HV), 128, 0, stream>>>(pn, Wq, Wk, Qh, Kh);

  { // krn[h,s,t] = mask(t<=s) * (Q.K)/sqrt(D) * wn[s]  -> bf16 (masked tiles skipped)
    GemmArgs g = {};
    g.A = Qh; g.B = Kh; g.Cb = krn;
    g.K = DV; g.lda = DV; g.ldb = DV; g.ldc = SV;
    g.sAh = (long)SV*DV; g.sBh = (long)SV*DV; g.sCh = (long)SV*SV;
    g.Hmod = HV; g.KC = 1; g.causal = 0;
    g.scale = 0.044194173824159216f;  // 1/sqrt(512)
    gemm_nt<3><<<dim3(SV/128, SV/128, HV), 256, 0, stream>>>(g);
  }

  // ---- layer 0: f_k==0 => R uniform => ex_wte/sumR == mean_v(wte) (exact) ----
  vt0_transpose_k<<<dim3(DV/32, SV/32, BV), dim3(32,8), 0, stream>>>(e, wmean, VtT);
  layer_tail0(krn, VtT, U_rs, Wo_b, f_k, f_k_b, hbuf, Gbuf, fpart,
              w1_b, w2_b, lnmw, stream);

  // ---- layer 1: PT = exp(f_k@wte^T); per-v Z and max-shift drop out of exw/colsum ----
  for (int b = 0; b < BV; b++) {
    float* partb = part + (long)b*(VV/128)*SV;
    { // PT(S,V) = exp(logits), fused partial colsum into part[b]
      GemmArgs g = {};
      g.A = f_k_b + (long)b*SV*DV; g.B = wte_b; g.Cb = PT; g.Cf = partb;
      g.K = DV; g.lda = DV; g.ldb = DV; g.ldc = VV;
      g.KC = 1;
      gemm256<5><<<dim3(SV/256, VV/256, 1), 512, 0, stream>>>(g);
    }
    { // expart[c] = partial of P'^T @ wte  (split-K=25 over V)
      GemmArgs g = {};
      g.A = PT; g.B = wteT_b; g.Cb = expart;
      g.K = VV; g.lda = VV; g.ldb = VV; g.ldc = DV;
      g.sCh = (long)SV*DV;
      g.KC = KCX;
      gemm256<7><<<dim3(SV/256, DV/256, KCX), 512, 0, stream>>>(g);
    }
    vt_part_k<<<dim3(DV/32, SV/32), dim3(32,8), 0, stream>>>(
        e + (long)b*SV*DV, expart, partb, VtT + (long)b*DV*SV);
  }

  // ---- layer-1 tail, last-row only (everything after the Wo add is row-wise
  // and only row SV-1 feeds the output logits) ----
  u_last_k<<<dim3(DV/4, HV, BV), 256, 0, stream>>>(krn, VtT, u_last);
  gemv_k<0><<<dim3(DV/4, BV), 256, 0, stream>>>(
      Wo_b + (long)1*DV*HV*DV, u_last, delta, nullptr, DV, HV*DV, (long)HV*DV);
  mid_ln_k<<<1, 128, 0, stream>>>(f_k, delta, lnmw, f_last, h_last);
  gemv_k<1><<<dim3(DFFV/4, BV), 256, 0, stream>>>(
      w1_b, h_last, nullptr, g_last, DFFV, DV, (long)DV);
  gemv_k<0><<<dim3(DV/4, BV), 256, 0, stream>>>(
      w2_b, g_last, o2buf, nullptr, DV, DFFV, (long)DFFV);
  final2_k<<<1, 128, 0, stream>>>(f_last, o2buf, lnfw, obuf);
  logits_k<<<dim3(VV/4), 256, 0, stream>>>(obuf, wte, out, VV);
}